// Round 1
// baseline (992.944 us; speedup 1.0000x reference)
//
#include <hip/hip_runtime.h>
#include <hip/hip_bf16.h>
#include <math.h>

#define N_NODES 50000
#define N_EDGES 800000
#define F_IN    64
#define F_HID   128
#define F_OUT   40

// ---------------- degree / norm ----------------

__global__ void k_init_deg(float* __restrict__ deg) {
    int i = blockIdx.x * blockDim.x + threadIdx.x;
    if (i < N_NODES) deg[i] = 1.0f;   // self loop
}

__global__ void k_deg_atomic(const int* __restrict__ ei, float* __restrict__ deg) {
    int e = blockIdx.x * blockDim.x + threadIdx.x;
    if (e < N_EDGES) unsafeAtomicAdd(&deg[ei[N_EDGES + e]], 1.0f);  // col = target
}

__global__ void k_rsqrt(float* __restrict__ deg) {
    int i = blockIdx.x * blockDim.x + threadIdx.x;
    if (i < N_NODES) deg[i] = rsqrtf(deg[i]);   // deg >= 1 always
}

// ---------------- layer 1: aggregate X (64 feats), then GEMM ----------------

// agg1[i] = dinv[i]^2 * x[i]   (self-loop term), float4-vectorized
__global__ void k_init_agg1(const float* __restrict__ x, const float* __restrict__ dinv,
                            float* __restrict__ agg1) {
    int idx = blockIdx.x * blockDim.x + threadIdx.x;   // N*16 float4s
    if (idx >= N_NODES * 16) return;
    int i = idx >> 4;
    float d = dinv[i];
    float s = d * d;
    float4 v = ((const float4*)x)[idx];
    v.x *= s; v.y *= s; v.z *= s; v.w *= s;
    ((float4*)agg1)[idx] = v;
}

// 16 threads per edge, one float4 each
__global__ void k_edge_agg1(const float* __restrict__ x, const int* __restrict__ ei,
                            const float* __restrict__ dinv, float* __restrict__ agg1) {
    int idx = blockIdx.x * blockDim.x + threadIdx.x;   // E*16
    if (idx >= N_EDGES * 16) return;
    int e = idx >> 4, q = idx & 15;
    int r = ei[e];             // source (row)
    int c = ei[N_EDGES + e];   // target (col)
    float nrm = dinv[r] * dinv[c];
    float4 v = ((const float4*)(x + (size_t)r * F_IN))[q];
    float* dst = agg1 + (size_t)c * F_IN + q * 4;
    unsafeAtomicAdd(dst + 0, v.x * nrm);
    unsafeAtomicAdd(dst + 1, v.y * nrm);
    unsafeAtomicAdd(dst + 2, v.z * nrm);
    unsafeAtomicAdd(dst + 3, v.w * nrm);
}

// h1 = PReLU(agg1 @ W1 + b1); W1 is 64x128 (32 KB) in LDS
__global__ __launch_bounds__(256) void k_gemm1(const float* __restrict__ agg1,
                                               const float* __restrict__ W1,
                                               const float* __restrict__ b1,
                                               const float* __restrict__ alpha,
                                               float* __restrict__ h1) {
    __shared__ float sW[F_IN * F_HID];
    __shared__ float sb[F_HID];
    int t = threadIdx.x;
    for (int i = t; i < F_IN * F_HID; i += 256) sW[i] = W1[i];
    if (t < F_HID) sb[t] = b1[t];
    __syncthreads();
    const float a = alpha[0];
    const int col  = t & 127;
    const int half = t >> 7;   // 0 or 1
    for (int it = 0; it < 16; ++it) {
        int r = blockIdx.x * 32 + half + it * 2;
        if (r >= N_NODES) break;
        const float* xr = agg1 + (size_t)r * F_IN;
        float acc = sb[col];
        #pragma unroll
        for (int k = 0; k < F_IN; ++k) acc = fmaf(xr[k], sW[k * F_HID + col], acc);
        h1[(size_t)r * F_HID + col] = (acc >= 0.f) ? acc : a * acc;
    }
}

// ---------------- layer 2: GEMM (128->40), then aggregate ----------------

__global__ __launch_bounds__(256) void k_gemm2(const float* __restrict__ h1,
                                               const float* __restrict__ W2,
                                               float* __restrict__ h2) {
    __shared__ float sW[F_HID * F_OUT];   // 20 KB
    int t = threadIdx.x;
    for (int i = t; i < F_HID * F_OUT; i += 256) sW[i] = W2[i];
    __syncthreads();
    int idx = blockIdx.x * 256 + t;
    if (idx >= N_NODES * F_OUT) return;
    int r = idx / F_OUT, c = idx % F_OUT;
    const float* xr = h1 + (size_t)r * F_HID;
    float acc = 0.f;
    #pragma unroll
    for (int k = 0; k < F_HID; ++k) acc = fmaf(xr[k], sW[k * F_OUT + c], acc);
    h2[idx] = acc;
}

// out[i] = dinv[i]^2 * h2[i]   (self-loop term of layer-2 aggregation)
__global__ void k_init_out(const float* __restrict__ h2, const float* __restrict__ dinv,
                           float* __restrict__ out) {
    int idx = blockIdx.x * blockDim.x + threadIdx.x;
    if (idx >= N_NODES * F_OUT) return;
    int i = idx / F_OUT;
    float d = dinv[i];
    out[idx] = h2[idx] * d * d;
}

// one thread per (edge, class)
__global__ void k_edge_agg2(const float* __restrict__ h2, const int* __restrict__ ei,
                            const float* __restrict__ dinv, float* __restrict__ out) {
    int idx = blockIdx.x * 256 + threadIdx.x;   // E*40 = 32M < 2^31
    if (idx >= N_EDGES * F_OUT) return;
    int e = idx / F_OUT, c = idx % F_OUT;
    int r  = ei[e];
    int cl = ei[N_EDGES + e];
    float nrm = dinv[r] * dinv[cl];
    unsafeAtomicAdd(&out[(size_t)cl * F_OUT + c], h2[(size_t)r * F_OUT + c] * nrm);
}

// in-place per-row log_softmax over 40 classes (+ bias b2); one wave per row
__global__ void k_logsoftmax(float* __restrict__ out, const float* __restrict__ b2) {
    int gid  = blockIdx.x * blockDim.x + threadIdx.x;
    int wave = gid >> 6;
    int lane = threadIdx.x & 63;
    if (wave >= N_NODES) return;
    float v = (lane < F_OUT) ? (out[(size_t)wave * F_OUT + lane] + b2[lane]) : -INFINITY;
    float m = v;
    #pragma unroll
    for (int o = 32; o > 0; o >>= 1) m = fmaxf(m, __shfl_xor(m, o));
    float ex = (lane < F_OUT) ? expf(v - m) : 0.f;
    float s = ex;
    #pragma unroll
    for (int o = 32; o > 0; o >>= 1) s += __shfl_xor(s, o);
    if (lane < F_OUT) out[(size_t)wave * F_OUT + lane] = v - m - logf(s);
}

// ---------------- launch ----------------

extern "C" void kernel_launch(void* const* d_in, const int* in_sizes, int n_in,
                              void* d_out, int out_size, void* d_ws, size_t ws_size,
                              hipStream_t stream) {
    const float* x     = (const float*)d_in[0];
    const int*   ei    = (const int*)d_in[1];     // [2, E] flattened: row then col
    const float* W1    = (const float*)d_in[2];
    const float* b1    = (const float*)d_in[3];
    const float* W2    = (const float*)d_in[4];
    const float* b2    = (const float*)d_in[5];
    const float* alpha = (const float*)d_in[6];
    float* out = (float*)d_out;

    char* ws = (char*)d_ws;
    float* dinv = (float*)ws;                                   // N floats (deg -> dinv in place)
    float* agg1 = (float*)(ws + 256 * 1024);                    // N*64
    float* h1   = agg1 + (size_t)N_NODES * F_IN;                // N*128
    float* h2   = h1   + (size_t)N_NODES * F_HID;               // N*40

    const int B = 256;

    hipLaunchKernelGGL(k_init_deg,  dim3((N_NODES + B - 1) / B), dim3(B), 0, stream, dinv);
    hipLaunchKernelGGL(k_deg_atomic, dim3((N_EDGES + B - 1) / B), dim3(B), 0, stream, ei, dinv);
    hipLaunchKernelGGL(k_rsqrt,     dim3((N_NODES + B - 1) / B), dim3(B), 0, stream, dinv);

    hipLaunchKernelGGL(k_init_agg1, dim3((N_NODES * 16 + B - 1) / B), dim3(B), 0, stream, x, dinv, agg1);
    hipLaunchKernelGGL(k_edge_agg1, dim3((N_EDGES * 16 + B - 1) / B), dim3(B), 0, stream, x, ei, dinv, agg1);

    hipLaunchKernelGGL(k_gemm1, dim3((N_NODES + 31) / 32), dim3(B), 0, stream, agg1, W1, b1, alpha, h1);
    hipLaunchKernelGGL(k_gemm2, dim3((N_NODES * F_OUT + B - 1) / B), dim3(B), 0, stream, h1, W2, h2);

    hipLaunchKernelGGL(k_init_out,  dim3((N_NODES * F_OUT + B - 1) / B), dim3(B), 0, stream, h2, dinv, out);
    hipLaunchKernelGGL(k_edge_agg2, dim3((N_EDGES * F_OUT + B - 1) / B), dim3(B), 0, stream, h2, ei, dinv, out);

    hipLaunchKernelGGL(k_logsoftmax, dim3((N_NODES * 64 + B - 1) / B), dim3(B), 0, stream, out, b2);
}

// Round 2
// 482.705 us; speedup vs baseline: 2.0570x; 2.0570x over previous
//
#include <hip/hip_runtime.h>
#include <hip/hip_bf16.h>
#include <math.h>

#define N_NODES 50000
#define N_EDGES 800000
#define F_IN    64
#define F_HID   128
#define F_OUT   40
#define SCAN_CHUNK 196   // ceil(50000/256)

// ---------------- CSR build ----------------

__global__ void k_zero_cnt(int* __restrict__ cnt) {
    int i = blockIdx.x * blockDim.x + threadIdx.x;
    if (i < N_NODES) cnt[i] = 0;
}

__global__ void k_count(const int* __restrict__ ei, int* __restrict__ cnt) {
    int e = blockIdx.x * blockDim.x + threadIdx.x;
    if (e < N_EDGES) atomicAdd(&cnt[ei[N_EDGES + e]], 1);   // target node
}

// single-block exclusive scan over 50000 counts (in place cnt -> start),
// also copies to cursor and derives dinv = rsqrt(deg+1)
__global__ __launch_bounds__(256) void k_scan(int* __restrict__ startArr,
                                              int* __restrict__ cursor,
                                              float* __restrict__ dinv) {
    __shared__ int part[256];
    int t = threadIdx.x;
    int base = t * SCAN_CHUNK;
    int n = N_NODES - base; if (n < 0) n = 0; if (n > SCAN_CHUNK) n = SCAN_CHUNK;
    int sum = 0;
    for (int i = 0; i < n; ++i) sum += startArr[base + i];
    part[t] = sum;
    __syncthreads();
    for (int off = 1; off < 256; off <<= 1) {
        int v = (t >= off) ? part[t - off] : 0;
        __syncthreads();
        part[t] += v;
        __syncthreads();
    }
    int run = part[t] - sum;   // exclusive prefix
    for (int i = 0; i < n; ++i) {
        int j = base + i;
        int v = startArr[j];
        startArr[j] = run;
        cursor[j]   = run;
        dinv[j]     = rsqrtf((float)v + 1.0f);   // +1 self loop
        run += v;
    }
    if (t == 255) startArr[N_NODES] = N_EDGES;
}

__global__ void k_scatter(const int* __restrict__ ei, int* __restrict__ cursor,
                          int* __restrict__ csr) {
    int e = blockIdx.x * blockDim.x + threadIdx.x;
    if (e >= N_EDGES) return;
    int r = ei[e];             // source
    int c = ei[N_EDGES + e];   // target
    int pos = atomicAdd(&cursor[c], 1);
    csr[pos] = r;
}

// ---------------- layer 1: gather-aggregate X (64 feats) ----------------

// one wave per target node; lane = feature
__global__ __launch_bounds__(256) void k_agg1(const float* __restrict__ x,
                                              const float* __restrict__ dinv,
                                              const int* __restrict__ startArr,
                                              const int* __restrict__ csr,
                                              float* __restrict__ agg1) {
    int wid  = (blockIdx.x * 256 + threadIdx.x) >> 6;
    int lane = threadIdx.x & 63;
    if (wid >= N_NODES) return;
    int c = wid;
    float dc = dinv[c];
    float acc = dc * dc * x[(size_t)c * F_IN + lane];   // self loop
    int e = startArr[c], eend = startArr[c + 1];
    for (; e + 1 < eend; e += 2) {
        int r0 = csr[e], r1 = csr[e + 1];
        float n0 = dinv[r0] * dc, n1 = dinv[r1] * dc;
        float v0 = x[(size_t)r0 * F_IN + lane];
        float v1 = x[(size_t)r1 * F_IN + lane];
        acc = fmaf(v0, n0, acc);
        acc = fmaf(v1, n1, acc);
    }
    if (e < eend) {
        int r0 = csr[e];
        acc = fmaf(x[(size_t)r0 * F_IN + lane], dinv[r0] * dc, acc);
    }
    agg1[(size_t)c * F_IN + lane] = acc;
}

// h1 = PReLU(agg1 @ W1 + b1); W1 64x128 in LDS
__global__ __launch_bounds__(256) void k_gemm1(const float* __restrict__ agg1,
                                               const float* __restrict__ W1,
                                               const float* __restrict__ b1,
                                               const float* __restrict__ alpha,
                                               float* __restrict__ h1) {
    __shared__ float sW[F_IN * F_HID];
    __shared__ float sb[F_HID];
    int t = threadIdx.x;
    for (int i = t; i < F_IN * F_HID; i += 256) sW[i] = W1[i];
    if (t < F_HID) sb[t] = b1[t];
    __syncthreads();
    const float a = alpha[0];
    const int col  = t & 127;
    const int half = t >> 7;
    for (int it = 0; it < 16; ++it) {
        int r = blockIdx.x * 32 + half + it * 2;
        if (r >= N_NODES) break;
        const float* xr = agg1 + (size_t)r * F_IN;
        float acc = sb[col];
        #pragma unroll
        for (int k = 0; k < F_IN; ++k) acc = fmaf(xr[k], sW[k * F_HID + col], acc);
        h1[(size_t)r * F_HID + col] = (acc >= 0.f) ? acc : a * acc;
    }
}

// ---------------- layer 2: GEMM 128->40, then gather-aggregate ----------------

__global__ __launch_bounds__(256) void k_gemm2(const float* __restrict__ h1,
                                               const float* __restrict__ W2,
                                               float* __restrict__ h2) {
    __shared__ float sW[F_HID * F_OUT];
    int t = threadIdx.x;
    for (int i = t; i < F_HID * F_OUT; i += 256) sW[i] = W2[i];
    __syncthreads();
    int idx = blockIdx.x * 256 + t;
    if (idx >= N_NODES * F_OUT) return;
    int r = idx / F_OUT, c = idx % F_OUT;
    const float* xr = h1 + (size_t)r * F_HID;
    float acc = 0.f;
    #pragma unroll
    for (int k = 0; k < F_HID; ++k) acc = fmaf(xr[k], sW[k * F_OUT + c], acc);
    h2[idx] = acc;
}

// one wave per node: gather-aggregate h2 (40 feats) + bias + log_softmax, write out
__global__ __launch_bounds__(256) void k_agg2_lsm(const float* __restrict__ h2,
                                                  const float* __restrict__ dinv,
                                                  const int* __restrict__ startArr,
                                                  const int* __restrict__ csr,
                                                  const float* __restrict__ b2,
                                                  float* __restrict__ out) {
    int wid  = (blockIdx.x * 256 + threadIdx.x) >> 6;
    int lane = threadIdx.x & 63;
    if (wid >= N_NODES) return;
    int c = wid;
    float dc = dinv[c];
    int e = startArr[c], eend = startArr[c + 1];
    float acc = 0.f;
    if (lane < F_OUT) {
        acc = dc * dc * h2[(size_t)c * F_OUT + lane];   // self loop
        for (int k = e; k < eend; ++k) {
            int r = csr[k];
            acc = fmaf(h2[(size_t)r * F_OUT + lane], dinv[r] * dc, acc);
        }
    }
    float v = (lane < F_OUT) ? (acc + b2[lane]) : -INFINITY;
    float m = v;
    #pragma unroll
    for (int o = 32; o > 0; o >>= 1) m = fmaxf(m, __shfl_xor(m, o));
    float ex = (lane < F_OUT) ? expf(v - m) : 0.f;
    float s = ex;
    #pragma unroll
    for (int o = 32; o > 0; o >>= 1) s += __shfl_xor(s, o);
    if (lane < F_OUT) out[(size_t)c * F_OUT + lane] = v - m - logf(s);
}

// ---------------- launch ----------------

extern "C" void kernel_launch(void* const* d_in, const int* in_sizes, int n_in,
                              void* d_out, int out_size, void* d_ws, size_t ws_size,
                              hipStream_t stream) {
    const float* x     = (const float*)d_in[0];
    const int*   ei    = (const int*)d_in[1];
    const float* W1    = (const float*)d_in[2];
    const float* b1    = (const float*)d_in[3];
    const float* W2    = (const float*)d_in[4];
    const float* b2    = (const float*)d_in[5];
    const float* alpha = (const float*)d_in[6];
    float* out = (float*)d_out;

    // workspace layout (elements), total ~42.2 MB
    int*   startArr = (int*)d_ws;                       // N+1 -> padded 50048
    int*   cursor   = startArr + 50048;                 // N   -> 50048
    int*   csr      = cursor + 50048;                   // E = 800000
    float* dinv     = (float*)(csr + N_EDGES);          // N   -> 50048
    float* h1       = dinv + 50048;                     // N*128 = 6.4M
    float* agg1     = h1 + (size_t)N_NODES * F_HID;     // N*64 = 3.2M
    float* h2       = agg1;                             // reuse (N*40 <= N*64)

    const int B = 256;

    hipLaunchKernelGGL(k_zero_cnt, dim3((N_NODES + B - 1) / B), dim3(B), 0, stream, startArr);
    hipLaunchKernelGGL(k_count,    dim3((N_EDGES + B - 1) / B), dim3(B), 0, stream, ei, startArr);
    hipLaunchKernelGGL(k_scan,     dim3(1), dim3(B), 0, stream, startArr, cursor, dinv);
    hipLaunchKernelGGL(k_scatter,  dim3((N_EDGES + B - 1) / B), dim3(B), 0, stream, ei, cursor, csr);

    hipLaunchKernelGGL(k_agg1,  dim3((N_NODES * 64 + B - 1) / B), dim3(B), 0, stream, x, dinv, startArr, csr, agg1);
    hipLaunchKernelGGL(k_gemm1, dim3((N_NODES + 31) / 32), dim3(B), 0, stream, agg1, W1, b1, alpha, h1);
    hipLaunchKernelGGL(k_gemm2, dim3((N_NODES * F_OUT + B - 1) / B), dim3(B), 0, stream, h1, W2, h2);
    hipLaunchKernelGGL(k_agg2_lsm, dim3((N_NODES * 64 + B - 1) / B), dim3(B), 0, stream,
                       h2, dinv, startArr, csr, b2, out);
}

// Round 3
// 340.439 us; speedup vs baseline: 2.9167x; 1.4179x over previous
//
#include <hip/hip_runtime.h>
#include <hip/hip_bf16.h>
#include <math.h>

#define N_NODES 50000
#define N_EDGES 800000
#define F_IN    64
#define F_HID   128
#define F_OUT   40
#define SCAN_BLOCKS 196   // ceil(50000/256)

// ---------------- CSR build ----------------

__global__ void k_zero_cnt(int* __restrict__ cnt) {
    int i = blockIdx.x * blockDim.x + threadIdx.x;
    if (i < N_NODES) cnt[i] = 0;
}

__global__ void k_count(const int* __restrict__ ei, int* __restrict__ cnt) {
    int e = blockIdx.x * blockDim.x + threadIdx.x;
    if (e < N_EDGES) atomicAdd(&cnt[ei[N_EDGES + e]], 1);   // target node
}

// phase A: per-block reduction of 256 counts -> blockSums[b]
__global__ __launch_bounds__(256) void k_scanA(const int* __restrict__ cnt,
                                               int* __restrict__ blockSums) {
    __shared__ int sw[4];
    int i = blockIdx.x * 256 + threadIdx.x;
    int v = (i < N_NODES) ? cnt[i] : 0;
    #pragma unroll
    for (int o = 32; o > 0; o >>= 1) v += __shfl_xor(v, o);
    int lane = threadIdx.x & 63, w = threadIdx.x >> 6;
    if (lane == 0) sw[w] = v;
    __syncthreads();
    if (threadIdx.x == 0) blockSums[blockIdx.x] = sw[0] + sw[1] + sw[2] + sw[3];
}

// phase B: single-block exclusive scan of SCAN_BLOCKS block sums
__global__ __launch_bounds__(256) void k_scanB(int* __restrict__ blockSums) {
    __shared__ int part[256];
    int t = threadIdx.x;
    int v = (t < SCAN_BLOCKS) ? blockSums[t] : 0;
    part[t] = v;
    __syncthreads();
    for (int off = 1; off < 256; off <<= 1) {
        int u = (t >= off) ? part[t - off] : 0;
        __syncthreads();
        part[t] += u;
        __syncthreads();
    }
    if (t < SCAN_BLOCKS) blockSums[t] = part[t] - v;   // exclusive
}

// phase C: intra-block exclusive scan + block offset; emit start/cursor/dinv
__global__ __launch_bounds__(256) void k_scanC(int* __restrict__ startArr,
                                               const int* __restrict__ blockSums,
                                               int* __restrict__ cursor,
                                               float* __restrict__ dinv) {
    __shared__ int part[256];
    int t = threadIdx.x;
    int i = blockIdx.x * 256 + t;
    int v = (i < N_NODES) ? startArr[i] : 0;
    part[t] = v;
    __syncthreads();
    for (int off = 1; off < 256; off <<= 1) {
        int u = (t >= off) ? part[t - off] : 0;
        __syncthreads();
        part[t] += u;
        __syncthreads();
    }
    if (i < N_NODES) {
        int pos = blockSums[blockIdx.x] + part[t] - v;   // exclusive prefix
        startArr[i] = pos;
        cursor[i]   = pos;
        dinv[i]     = rsqrtf((float)v + 1.0f);           // +1 self loop
    }
    if (i == 0) startArr[N_NODES] = N_EDGES;
}

__global__ void k_scatter(const int* __restrict__ ei, int* __restrict__ cursor,
                          int* __restrict__ csr) {
    int e = blockIdx.x * blockDim.x + threadIdx.x;
    if (e >= N_EDGES) return;
    int r = ei[e];             // source
    int c = ei[N_EDGES + e];   // target
    int pos = atomicAdd(&cursor[c], 1);
    csr[pos] = r;
}

// ---------------- layer 1: gather-aggregate X (64 feats) ----------------

// one wave per target node; lane = feature
__global__ __launch_bounds__(256) void k_agg1(const float* __restrict__ x,
                                              const float* __restrict__ dinv,
                                              const int* __restrict__ startArr,
                                              const int* __restrict__ csr,
                                              float* __restrict__ agg1) {
    int wid  = (blockIdx.x * 256 + threadIdx.x) >> 6;
    int lane = threadIdx.x & 63;
    if (wid >= N_NODES) return;
    int c = wid;
    float dc = dinv[c];
    float acc = dc * dc * x[(size_t)c * F_IN + lane];   // self loop
    int e = startArr[c], eend = startArr[c + 1];
    for (; e + 1 < eend; e += 2) {
        int r0 = csr[e], r1 = csr[e + 1];
        float n0 = dinv[r0] * dc, n1 = dinv[r1] * dc;
        float v0 = x[(size_t)r0 * F_IN + lane];
        float v1 = x[(size_t)r1 * F_IN + lane];
        acc = fmaf(v0, n0, acc);
        acc = fmaf(v1, n1, acc);
    }
    if (e < eend) {
        int r0 = csr[e];
        acc = fmaf(x[(size_t)r0 * F_IN + lane], dinv[r0] * dc, acc);
    }
    agg1[(size_t)c * F_IN + lane] = acc;
}

// h1 = PReLU(agg1 @ W1 + b1); W1 64x128 in LDS
__global__ __launch_bounds__(256) void k_gemm1(const float* __restrict__ agg1,
                                               const float* __restrict__ W1,
                                               const float* __restrict__ b1,
                                               const float* __restrict__ alpha,
                                               float* __restrict__ h1) {
    __shared__ float sW[F_IN * F_HID];
    __shared__ float sb[F_HID];
    int t = threadIdx.x;
    for (int i = t; i < F_IN * F_HID; i += 256) sW[i] = W1[i];
    if (t < F_HID) sb[t] = b1[t];
    __syncthreads();
    const float a = alpha[0];
    const int col  = t & 127;
    const int half = t >> 7;
    for (int it = 0; it < 16; ++it) {
        int r = blockIdx.x * 32 + half + it * 2;
        if (r >= N_NODES) break;
        const float* xr = agg1 + (size_t)r * F_IN;
        float acc = sb[col];
        #pragma unroll
        for (int k = 0; k < F_IN; ++k) acc = fmaf(xr[k], sW[k * F_HID + col], acc);
        h1[(size_t)r * F_HID + col] = (acc >= 0.f) ? acc : a * acc;
    }
}

// ---------------- layer 2: GEMM 128->40, then gather-aggregate ----------------

__global__ __launch_bounds__(256) void k_gemm2(const float* __restrict__ h1,
                                               const float* __restrict__ W2,
                                               float* __restrict__ h2) {
    __shared__ float sW[F_HID * F_OUT];
    int t = threadIdx.x;
    for (int i = t; i < F_HID * F_OUT; i += 256) sW[i] = W2[i];
    __syncthreads();
    int idx = blockIdx.x * 256 + t;
    if (idx >= N_NODES * F_OUT) return;
    int r = idx / F_OUT, c = idx % F_OUT;
    const float* xr = h1 + (size_t)r * F_HID;
    float acc = 0.f;
    #pragma unroll
    for (int k = 0; k < F_HID; ++k) acc = fmaf(xr[k], sW[k * F_OUT + c], acc);
    h2[idx] = acc;
}

// one wave per node: gather-aggregate h2 (40 feats) + bias + log_softmax, write out
__global__ __launch_bounds__(256) void k_agg2_lsm(const float* __restrict__ h2,
                                                  const float* __restrict__ dinv,
                                                  const int* __restrict__ startArr,
                                                  const int* __restrict__ csr,
                                                  const float* __restrict__ b2,
                                                  float* __restrict__ out) {
    int wid  = (blockIdx.x * 256 + threadIdx.x) >> 6;
    int lane = threadIdx.x & 63;
    if (wid >= N_NODES) return;
    int c = wid;
    float dc = dinv[c];
    int e = startArr[c], eend = startArr[c + 1];
    float acc = 0.f;
    if (lane < F_OUT) {
        acc = dc * dc * h2[(size_t)c * F_OUT + lane];   // self loop
        for (int k = e; k < eend; ++k) {
            int r = csr[k];
            acc = fmaf(h2[(size_t)r * F_OUT + lane], dinv[r] * dc, acc);
        }
    }
    float v = (lane < F_OUT) ? (acc + b2[lane]) : -INFINITY;
    float m = v;
    #pragma unroll
    for (int o = 32; o > 0; o >>= 1) m = fmaxf(m, __shfl_xor(m, o));
    float ex = (lane < F_OUT) ? expf(v - m) : 0.f;
    float s = ex;
    #pragma unroll
    for (int o = 32; o > 0; o >>= 1) s += __shfl_xor(s, o);
    if (lane < F_OUT) out[(size_t)c * F_OUT + lane] = v - m - logf(s);
}

// ---------------- launch ----------------

extern "C" void kernel_launch(void* const* d_in, const int* in_sizes, int n_in,
                              void* d_out, int out_size, void* d_ws, size_t ws_size,
                              hipStream_t stream) {
    const float* x     = (const float*)d_in[0];
    const int*   ei    = (const int*)d_in[1];
    const float* W1    = (const float*)d_in[2];
    const float* b1    = (const float*)d_in[3];
    const float* W2    = (const float*)d_in[4];
    const float* b2    = (const float*)d_in[5];
    const float* alpha = (const float*)d_in[6];
    float* out = (float*)d_out;

    // workspace layout (elements)
    int*   startArr  = (int*)d_ws;                       // N+1 -> padded 50048
    int*   cursor    = startArr + 50048;                 // N   -> 50048
    int*   blockSums = cursor + 50048;                   // 256
    int*   csr       = blockSums + 256;                  // E = 800000
    float* dinv      = (float*)(csr + N_EDGES);          // N   -> 50048
    float* h1        = dinv + 50048;                     // N*128 = 6.4M
    float* agg1      = h1 + (size_t)N_NODES * F_HID;     // N*64 = 3.2M
    float* h2        = agg1;                             // reuse (N*40 <= N*64)

    const int B = 256;

    hipLaunchKernelGGL(k_zero_cnt, dim3((N_NODES + B - 1) / B), dim3(B), 0, stream, startArr);
    hipLaunchKernelGGL(k_count,    dim3((N_EDGES + B - 1) / B), dim3(B), 0, stream, ei, startArr);
    hipLaunchKernelGGL(k_scanA,    dim3(SCAN_BLOCKS), dim3(B), 0, stream, startArr, blockSums);
    hipLaunchKernelGGL(k_scanB,    dim3(1), dim3(B), 0, stream, blockSums);
    hipLaunchKernelGGL(k_scanC,    dim3(SCAN_BLOCKS), dim3(B), 0, stream, startArr, blockSums, cursor, dinv);
    hipLaunchKernelGGL(k_scatter,  dim3((N_EDGES + B - 1) / B), dim3(B), 0, stream, ei, cursor, csr);

    hipLaunchKernelGGL(k_agg1,  dim3((N_NODES * 64 + B - 1) / B), dim3(B), 0, stream, x, dinv, startArr, csr, agg1);
    hipLaunchKernelGGL(k_gemm1, dim3((N_NODES + 31) / 32), dim3(B), 0, stream, agg1, W1, b1, alpha, h1);
    hipLaunchKernelGGL(k_gemm2, dim3((N_NODES * F_OUT + B - 1) / B), dim3(B), 0, stream, h1, W2, h2);
    hipLaunchKernelGGL(k_agg2_lsm, dim3((N_NODES * 64 + B - 1) / B), dim3(B), 0, stream,
                       h2, dinv, startArr, csr, b2, out);
}

// Round 4
// 268.452 us; speedup vs baseline: 3.6988x; 1.2682x over previous
//
#include <hip/hip_runtime.h>
#include <hip/hip_bf16.h>
#include <math.h>

#define N_NODES 50000
#define N_EDGES 800000
#define F_IN    64
#define F_HID   128
#define F_OUT   40
#define SCAN_BLOCKS 196   // ceil(50000/256)

// ---------------- CSR build ----------------

__global__ void k_zero_cnt(int* __restrict__ cnt) {
    int i = blockIdx.x * blockDim.x + threadIdx.x;
    if (i < N_NODES) cnt[i] = 0;
}

__global__ void k_count(const int* __restrict__ ei, int* __restrict__ cnt) {
    int e = blockIdx.x * blockDim.x + threadIdx.x;
    if (e < N_EDGES) atomicAdd(&cnt[ei[N_EDGES + e]], 1);   // target node
}

// phase A: per-block reduction of 256 counts -> blockSums[b]
__global__ __launch_bounds__(256) void k_scanA(const int* __restrict__ cnt,
                                               int* __restrict__ blockSums) {
    __shared__ int sw[4];
    int i = blockIdx.x * 256 + threadIdx.x;
    int v = (i < N_NODES) ? cnt[i] : 0;
    #pragma unroll
    for (int o = 32; o > 0; o >>= 1) v += __shfl_xor(v, o);
    int lane = threadIdx.x & 63, w = threadIdx.x >> 6;
    if (lane == 0) sw[w] = v;
    __syncthreads();
    if (threadIdx.x == 0) blockSums[blockIdx.x] = sw[0] + sw[1] + sw[2] + sw[3];
}

// phase B: single-block exclusive scan of SCAN_BLOCKS block sums
__global__ __launch_bounds__(256) void k_scanB(int* __restrict__ blockSums) {
    __shared__ int part[256];
    int t = threadIdx.x;
    int v = (t < SCAN_BLOCKS) ? blockSums[t] : 0;
    part[t] = v;
    __syncthreads();
    for (int off = 1; off < 256; off <<= 1) {
        int u = (t >= off) ? part[t - off] : 0;
        __syncthreads();
        part[t] += u;
        __syncthreads();
    }
    if (t < SCAN_BLOCKS) blockSums[t] = part[t] - v;   // exclusive
}

// phase C: intra-block exclusive scan + block offset; emit start/cursor/dinv
__global__ __launch_bounds__(256) void k_scanC(int* __restrict__ startArr,
                                               const int* __restrict__ blockSums,
                                               int* __restrict__ cursor,
                                               float* __restrict__ dinv) {
    __shared__ int part[256];
    int t = threadIdx.x;
    int i = blockIdx.x * 256 + t;
    int v = (i < N_NODES) ? startArr[i] : 0;
    part[t] = v;
    __syncthreads();
    for (int off = 1; off < 256; off <<= 1) {
        int u = (t >= off) ? part[t - off] : 0;
        __syncthreads();
        part[t] += u;
        __syncthreads();
    }
    if (i < N_NODES) {
        int pos = blockSums[blockIdx.x] + part[t] - v;   // exclusive prefix
        startArr[i] = pos;
        cursor[i]   = pos;
        dinv[i]     = rsqrtf((float)v + 1.0f);           // +1 self loop
    }
    if (i == 0) startArr[N_NODES] = N_EDGES;
}

__global__ void k_scatter(const int* __restrict__ ei, int* __restrict__ cursor,
                          int* __restrict__ csr) {
    int e = blockIdx.x * blockDim.x + threadIdx.x;
    if (e >= N_EDGES) return;
    int r = ei[e];             // source
    int c = ei[N_EDGES + e];   // target
    int pos = atomicAdd(&cursor[c], 1);
    csr[pos] = r;
}

// ---------------- x -> bf16 copy ----------------

__global__ void k_x2bf(const float* __restrict__ x, __hip_bfloat16* __restrict__ xb) {
    int i = blockIdx.x * 256 + threadIdx.x;   // over N*16 float4s
    if (i >= N_NODES * 16) return;
    float4 v = ((const float4*)x)[i];
    __hip_bfloat16 o[4] = { __float2bfloat16(v.x), __float2bfloat16(v.y),
                            __float2bfloat16(v.z), __float2bfloat16(v.w) };
    ((ushort4*)xb)[i] = *(const ushort4*)o;
}

// ---------------- layer 1: gather-aggregate X (64 feats, bf16 src) ----------------

// one wave per target node; lane = feature; edge batch preloaded by all lanes
__global__ __launch_bounds__(256) void k_agg1(const __hip_bfloat16* __restrict__ xb,
                                              const float* __restrict__ dinv,
                                              const int* __restrict__ startArr,
                                              const int* __restrict__ csr,
                                              float* __restrict__ agg1) {
    int wid  = (blockIdx.x * 256 + threadIdx.x) >> 6;
    int lane = threadIdx.x & 63;
    if (wid >= N_NODES) return;
    int c = wid;
    float dc = dinv[c];
    float acc = dc * dc * __bfloat162float(xb[(size_t)c * F_IN + lane]);   // self loop
    int e = startArr[c], eend = startArr[c + 1];
    while (e < eend) {
        int take = eend - e; if (take > 64) take = 64;
        int r = 0; float w = 0.f;
        if (lane < take) { r = csr[e + lane]; w = dinv[r] * dc; }
        int j = 0;
        for (; j + 3 < take; j += 4) {
            int   r0 = __shfl(r, j),     r1 = __shfl(r, j + 1);
            int   r2 = __shfl(r, j + 2), r3 = __shfl(r, j + 3);
            float w0 = __shfl(w, j),     w1 = __shfl(w, j + 1);
            float w2 = __shfl(w, j + 2), w3 = __shfl(w, j + 3);
            float v0 = __bfloat162float(xb[(size_t)r0 * F_IN + lane]);
            float v1 = __bfloat162float(xb[(size_t)r1 * F_IN + lane]);
            float v2 = __bfloat162float(xb[(size_t)r2 * F_IN + lane]);
            float v3 = __bfloat162float(xb[(size_t)r3 * F_IN + lane]);
            acc = fmaf(v0, w0, acc);
            acc = fmaf(v1, w1, acc);
            acc = fmaf(v2, w2, acc);
            acc = fmaf(v3, w3, acc);
        }
        for (; j < take; ++j) {
            int   rj = __shfl(r, j);
            float wj = __shfl(w, j);
            acc = fmaf(__bfloat162float(xb[(size_t)rj * F_IN + lane]), wj, acc);
        }
        e += take;
    }
    agg1[(size_t)c * F_IN + lane] = acc;
}

// h1 = PReLU(agg1 @ W1 + b1); W1 64x128 in LDS
__global__ __launch_bounds__(256) void k_gemm1(const float* __restrict__ agg1,
                                               const float* __restrict__ W1,
                                               const float* __restrict__ b1,
                                               const float* __restrict__ alpha,
                                               float* __restrict__ h1) {
    __shared__ float sW[F_IN * F_HID];
    __shared__ float sb[F_HID];
    int t = threadIdx.x;
    for (int i = t; i < F_IN * F_HID; i += 256) sW[i] = W1[i];
    if (t < F_HID) sb[t] = b1[t];
    __syncthreads();
    const float a = alpha[0];
    const int col  = t & 127;
    const int half = t >> 7;
    for (int it = 0; it < 16; ++it) {
        int r = blockIdx.x * 32 + half + it * 2;
        if (r >= N_NODES) break;
        const float* xr = agg1 + (size_t)r * F_IN;
        float acc = sb[col];
        #pragma unroll
        for (int k = 0; k < F_IN; ++k) acc = fmaf(xr[k], sW[k * F_HID + col], acc);
        h1[(size_t)r * F_HID + col] = (acc >= 0.f) ? acc : a * acc;
    }
}

// ---------------- layer 2: GEMM 128->40 (bf16 out), then gather-aggregate ----------------

__global__ __launch_bounds__(256) void k_gemm2(const float* __restrict__ h1,
                                               const float* __restrict__ W2,
                                               __hip_bfloat16* __restrict__ h2b) {
    __shared__ float sW[F_HID * F_OUT];
    int t = threadIdx.x;
    for (int i = t; i < F_HID * F_OUT; i += 256) sW[i] = W2[i];
    __syncthreads();
    int idx = blockIdx.x * 256 + t;
    if (idx >= N_NODES * F_OUT) return;
    int r = idx / F_OUT, c = idx % F_OUT;
    const float* xr = h1 + (size_t)r * F_HID;
    float acc = 0.f;
    #pragma unroll
    for (int k = 0; k < F_HID; ++k) acc = fmaf(xr[k], sW[k * F_OUT + c], acc);
    h2b[idx] = __float2bfloat16(acc);
}

// one wave per node: gather-aggregate h2b (40 feats) + bias + log_softmax
__global__ __launch_bounds__(256) void k_agg2_lsm(const __hip_bfloat16* __restrict__ h2b,
                                                  const float* __restrict__ dinv,
                                                  const int* __restrict__ startArr,
                                                  const int* __restrict__ csr,
                                                  const float* __restrict__ b2,
                                                  float* __restrict__ out) {
    int wid  = (blockIdx.x * 256 + threadIdx.x) >> 6;
    int lane = threadIdx.x & 63;
    if (wid >= N_NODES) return;
    int c = wid;
    float dc = dinv[c];
    float acc = 0.f;
    if (lane < F_OUT) acc = dc * dc * __bfloat162float(h2b[(size_t)c * F_OUT + lane]);
    int e = startArr[c], eend = startArr[c + 1];
    while (e < eend) {
        int take = eend - e; if (take > 64) take = 64;
        int r = 0; float w = 0.f;
        if (lane < take) { r = csr[e + lane]; w = dinv[r] * dc; }
        int j = 0;
        for (; j + 3 < take; j += 4) {
            int   r0 = __shfl(r, j),     r1 = __shfl(r, j + 1);
            int   r2 = __shfl(r, j + 2), r3 = __shfl(r, j + 3);
            float w0 = __shfl(w, j),     w1 = __shfl(w, j + 1);
            float w2 = __shfl(w, j + 2), w3 = __shfl(w, j + 3);
            if (lane < F_OUT) {
                float v0 = __bfloat162float(h2b[(size_t)r0 * F_OUT + lane]);
                float v1 = __bfloat162float(h2b[(size_t)r1 * F_OUT + lane]);
                float v2 = __bfloat162float(h2b[(size_t)r2 * F_OUT + lane]);
                float v3 = __bfloat162float(h2b[(size_t)r3 * F_OUT + lane]);
                acc = fmaf(v0, w0, acc);
                acc = fmaf(v1, w1, acc);
                acc = fmaf(v2, w2, acc);
                acc = fmaf(v3, w3, acc);
            }
        }
        for (; j < take; ++j) {
            int   rj = __shfl(r, j);
            float wj = __shfl(w, j);
            if (lane < F_OUT)
                acc = fmaf(__bfloat162float(h2b[(size_t)rj * F_OUT + lane]), wj, acc);
        }
        e += take;
    }
    float v = (lane < F_OUT) ? (acc + b2[lane]) : -INFINITY;
    float m = v;
    #pragma unroll
    for (int o = 32; o > 0; o >>= 1) m = fmaxf(m, __shfl_xor(m, o));
    float ex = (lane < F_OUT) ? expf(v - m) : 0.f;
    float s = ex;
    #pragma unroll
    for (int o = 32; o > 0; o >>= 1) s += __shfl_xor(s, o);
    if (lane < F_OUT) out[(size_t)c * F_OUT + lane] = v - m - logf(s);
}

// ---------------- launch ----------------

extern "C" void kernel_launch(void* const* d_in, const int* in_sizes, int n_in,
                              void* d_out, int out_size, void* d_ws, size_t ws_size,
                              hipStream_t stream) {
    const float* x     = (const float*)d_in[0];
    const int*   ei    = (const int*)d_in[1];
    const float* W1    = (const float*)d_in[2];
    const float* b1    = (const float*)d_in[3];
    const float* W2    = (const float*)d_in[4];
    const float* b2    = (const float*)d_in[5];
    const float* alpha = (const float*)d_in[6];
    float* out = (float*)d_out;

    // workspace layout (elements); bf16 buffers alias dead fp32 regions
    int*   startArr  = (int*)d_ws;                        // 50048 ints
    int*   cursor    = startArr + 50048;                  // 50048
    int*   blockSums = cursor + 50048;                    // 256
    int*   csr       = blockSums + 256;                   // 800000
    float* dinv      = (float*)(csr + N_EDGES);           // 50048 floats
    float* h1        = dinv + 50048;                      // N*128 fp32 (25.6 MB)
    __hip_bfloat16* xb  = (__hip_bfloat16*)h1;            // N*64 bf16, dead before gemm1 writes h1
    float* agg1f     = h1 + (size_t)N_NODES * F_HID;      // N*64 fp32 (12.8 MB)
    __hip_bfloat16* h2b = (__hip_bfloat16*)agg1f;         // N*40 bf16, dead before gemm2 writes

    const int B = 256;

    hipLaunchKernelGGL(k_zero_cnt, dim3((N_NODES + B - 1) / B), dim3(B), 0, stream, startArr);
    hipLaunchKernelGGL(k_count,    dim3((N_EDGES + B - 1) / B), dim3(B), 0, stream, ei, startArr);
    hipLaunchKernelGGL(k_scanA,    dim3(SCAN_BLOCKS), dim3(B), 0, stream, startArr, blockSums);
    hipLaunchKernelGGL(k_scanB,    dim3(1), dim3(B), 0, stream, blockSums);
    hipLaunchKernelGGL(k_scanC,    dim3(SCAN_BLOCKS), dim3(B), 0, stream, startArr, blockSums, cursor, dinv);
    hipLaunchKernelGGL(k_scatter,  dim3((N_EDGES + B - 1) / B), dim3(B), 0, stream, ei, cursor, csr);

    hipLaunchKernelGGL(k_x2bf,  dim3((N_NODES * 16 + B - 1) / B), dim3(B), 0, stream, x, xb);
    hipLaunchKernelGGL(k_agg1,  dim3((N_NODES * 64 + B - 1) / B), dim3(B), 0, stream, xb, dinv, startArr, csr, agg1f);
    hipLaunchKernelGGL(k_gemm1, dim3((N_NODES + 31) / 32), dim3(B), 0, stream, agg1f, W1, b1, alpha, h1);
    hipLaunchKernelGGL(k_gemm2, dim3((N_NODES * F_OUT + B - 1) / B), dim3(B), 0, stream, h1, W2, h2b);
    hipLaunchKernelGGL(k_agg2_lsm, dim3((N_NODES * 64 + B - 1) / B), dim3(B), 0, stream,
                       h2b, dinv, startArr, csr, b2, out);
}

// Round 5
// 206.550 us; speedup vs baseline: 4.8073x; 1.2997x over previous
//
#include <hip/hip_runtime.h>
#include <hip/hip_bf16.h>
#include <math.h>

#define N_NODES 50000
#define N_EDGES 800000
#define F_IN    64
#define F_HID   128
#define F_OUT   40
#define SCAN_BLOCKS 196   // ceil(50000/256)

// ---------------- CSR build ----------------

__global__ void k_zero_cnt(int* __restrict__ cnt) {
    int i = blockIdx.x * blockDim.x + threadIdx.x;
    if (i < N_NODES) cnt[i] = 0;
}

__global__ void k_count(const int* __restrict__ ei, int* __restrict__ cnt) {
    int e = blockIdx.x * blockDim.x + threadIdx.x;
    if (e < N_EDGES) atomicAdd(&cnt[ei[N_EDGES + e]], 1);   // target node
}

// phase A: per-block reduction of 256 counts -> blockSums[b]
__global__ __launch_bounds__(256) void k_scanA(const int* __restrict__ cnt,
                                               int* __restrict__ blockSums) {
    __shared__ int sw[4];
    int i = blockIdx.x * 256 + threadIdx.x;
    int v = (i < N_NODES) ? cnt[i] : 0;
    #pragma unroll
    for (int o = 32; o > 0; o >>= 1) v += __shfl_xor(v, o);
    int lane = threadIdx.x & 63, w = threadIdx.x >> 6;
    if (lane == 0) sw[w] = v;
    __syncthreads();
    if (threadIdx.x == 0) blockSums[blockIdx.x] = sw[0] + sw[1] + sw[2] + sw[3];
}

// phase B: single-block exclusive scan of SCAN_BLOCKS block sums
__global__ __launch_bounds__(256) void k_scanB(int* __restrict__ blockSums) {
    __shared__ int part[256];
    int t = threadIdx.x;
    int v = (t < SCAN_BLOCKS) ? blockSums[t] : 0;
    part[t] = v;
    __syncthreads();
    for (int off = 1; off < 256; off <<= 1) {
        int u = (t >= off) ? part[t - off] : 0;
        __syncthreads();
        part[t] += u;
        __syncthreads();
    }
    if (t < SCAN_BLOCKS) blockSums[t] = part[t] - v;   // exclusive
}

// phase C: intra-block exclusive scan + block offset; emit start/cursor/dinv
__global__ __launch_bounds__(256) void k_scanC(int* __restrict__ startArr,
                                               const int* __restrict__ blockSums,
                                               int* __restrict__ cursor,
                                               float* __restrict__ dinv) {
    __shared__ int part[256];
    int t = threadIdx.x;
    int i = blockIdx.x * 256 + t;
    int v = (i < N_NODES) ? startArr[i] : 0;
    part[t] = v;
    __syncthreads();
    for (int off = 1; off < 256; off <<= 1) {
        int u = (t >= off) ? part[t - off] : 0;
        __syncthreads();
        part[t] += u;
        __syncthreads();
    }
    if (i < N_NODES) {
        int pos = blockSums[blockIdx.x] + part[t] - v;   // exclusive prefix
        startArr[i] = pos;
        cursor[i]   = pos;
        dinv[i]     = rsqrtf((float)v + 1.0f);           // +1 self loop
    }
    if (i == 0) startArr[N_NODES] = N_EDGES;
}

__global__ void k_scatter(const int* __restrict__ ei, int* __restrict__ cursor,
                          int* __restrict__ csr) {
    int e = blockIdx.x * blockDim.x + threadIdx.x;
    if (e >= N_EDGES) return;
    int r = ei[e];             // source
    int c = ei[N_EDGES + e];   // target
    int pos = atomicAdd(&cursor[c], 1);
    csr[pos] = r;
}

// ---------------- x -> bf16 copy ----------------

__global__ void k_x2bf(const float* __restrict__ x, __hip_bfloat16* __restrict__ xb) {
    int i = blockIdx.x * 256 + threadIdx.x;   // over N*16 float4s
    if (i >= N_NODES * 16) return;
    float4 v = ((const float4*)x)[i];
    __hip_bfloat16 o[4] = { __float2bfloat16(v.x), __float2bfloat16(v.y),
                            __float2bfloat16(v.z), __float2bfloat16(v.w) };
    ((ushort4*)xb)[i] = *(const ushort4*)o;
}

// ---------------- layer 1: gather-aggregate X (64 feats, bf16 src) ----------------

__global__ __launch_bounds__(256) void k_agg1(const __hip_bfloat16* __restrict__ xb,
                                              const float* __restrict__ dinv,
                                              const int* __restrict__ startArr,
                                              const int* __restrict__ csr,
                                              float* __restrict__ agg1) {
    int wid  = (blockIdx.x * 256 + threadIdx.x) >> 6;
    int lane = threadIdx.x & 63;
    if (wid >= N_NODES) return;
    int c = wid;
    float dc = dinv[c];
    float acc = dc * dc * __bfloat162float(xb[(size_t)c * F_IN + lane]);   // self loop
    int e = startArr[c], eend = startArr[c + 1];
    while (e < eend) {
        int take = eend - e; if (take > 64) take = 64;
        int r = 0; float w = 0.f;
        if (lane < take) { r = csr[e + lane]; w = dinv[r] * dc; }
        int j = 0;
        for (; j + 3 < take; j += 4) {
            int   r0 = __shfl(r, j),     r1 = __shfl(r, j + 1);
            int   r2 = __shfl(r, j + 2), r3 = __shfl(r, j + 3);
            float w0 = __shfl(w, j),     w1 = __shfl(w, j + 1);
            float w2 = __shfl(w, j + 2), w3 = __shfl(w, j + 3);
            float v0 = __bfloat162float(xb[(size_t)r0 * F_IN + lane]);
            float v1 = __bfloat162float(xb[(size_t)r1 * F_IN + lane]);
            float v2 = __bfloat162float(xb[(size_t)r2 * F_IN + lane]);
            float v3 = __bfloat162float(xb[(size_t)r3 * F_IN + lane]);
            acc = fmaf(v0, w0, acc);
            acc = fmaf(v1, w1, acc);
            acc = fmaf(v2, w2, acc);
            acc = fmaf(v3, w3, acc);
        }
        for (; j < take; ++j) {
            int   rj = __shfl(r, j);
            float wj = __shfl(w, j);
            acc = fmaf(__bfloat162float(xb[(size_t)rj * F_IN + lane]), wj, acc);
        }
        e += take;
    }
    agg1[(size_t)c * F_IN + lane] = acc;
}

// ---------------- layer 1 GEMM: h1b = PReLU(agg1 @ W1 + b1), bf16 out ----------------
// tile: 64 rows x 128 cols; thread = 4 rows x 8 cols register block

__global__ __launch_bounds__(256) void k_gemm1(const float* __restrict__ agg1,
                                               const float* __restrict__ W1,
                                               const float* __restrict__ b1,
                                               const float* __restrict__ alpha,
                                               __hip_bfloat16* __restrict__ h1b) {
    __shared__ float sA[64][F_IN + 1];    // 64x65 fp32, pad kills bank conflicts
    __shared__ float sW[F_IN][F_HID];     // 32 KB
    __shared__ float sb[F_HID];
    int t = threadIdx.x;
    int row0 = blockIdx.x * 64;

    for (int i = t; i < (F_IN * F_HID) / 4; i += 256)
        ((float4*)sW)[i] = ((const float4*)W1)[i];
    if (t < F_HID) sb[t] = b1[t];
    for (int i = t; i < (64 * F_IN) / 4; i += 256) {
        int r = (i * 4) / F_IN, c = (i * 4) & (F_IN - 1);
        int rs = row0 + r; if (rs >= N_NODES) rs = N_NODES - 1;
        float4 v = *(const float4*)(agg1 + (size_t)rs * F_IN + c);
        sA[r][c] = v.x; sA[r][c + 1] = v.y; sA[r][c + 2] = v.z; sA[r][c + 3] = v.w;
    }
    __syncthreads();

    const int ri = (t >> 4) * 4;     // row block (0..60)
    const int cj = (t & 15) * 8;     // col block (0..120)
    float acc[4][8] = {};
    #pragma unroll 4
    for (int k = 0; k < F_IN; ++k) {
        float a0 = sA[ri + 0][k], a1 = sA[ri + 1][k];
        float a2 = sA[ri + 2][k], a3 = sA[ri + 3][k];
        float4 bA = *(const float4*)&sW[k][cj];
        float4 bB = *(const float4*)&sW[k][cj + 4];
        float bv[8] = { bA.x, bA.y, bA.z, bA.w, bB.x, bB.y, bB.z, bB.w };
        #pragma unroll
        for (int cc = 0; cc < 8; ++cc) {
            acc[0][cc] = fmaf(a0, bv[cc], acc[0][cc]);
            acc[1][cc] = fmaf(a1, bv[cc], acc[1][cc]);
            acc[2][cc] = fmaf(a2, bv[cc], acc[2][cc]);
            acc[3][cc] = fmaf(a3, bv[cc], acc[3][cc]);
        }
    }

    const float al = alpha[0];
    #pragma unroll
    for (int rr = 0; rr < 4; ++rr) {
        int r = row0 + ri + rr;
        if (r >= N_NODES) break;
        __hip_bfloat16 o[8];
        #pragma unroll
        for (int cc = 0; cc < 8; ++cc) {
            float v = acc[rr][cc] + sb[cj + cc];
            v = (v >= 0.f) ? v : al * v;
            o[cc] = __float2bfloat16(v);
        }
        *(float4*)(h1b + (size_t)r * F_HID + cj) = *(const float4*)o;   // 16B store
    }
}

// ---------------- layer 2 GEMM: h2b = h1b @ W2, bf16 in/out ----------------
// tile: 64 rows x 40 cols; thread = 2 rows x 5 cols

__global__ __launch_bounds__(256) void k_gemm2(const __hip_bfloat16* __restrict__ h1b,
                                               const float* __restrict__ W2,
                                               __hip_bfloat16* __restrict__ h2b) {
    __shared__ __hip_bfloat16 sA[64][F_HID + 8];   // 64x136 bf16, 16B-aligned rows
    __shared__ float sW[F_HID][F_OUT];             // 20 KB
    int t = threadIdx.x;
    int row0 = blockIdx.x * 64;

    for (int i = t; i < (F_HID * F_OUT) / 4; i += 256)
        ((float4*)sW)[i] = ((const float4*)W2)[i];
    for (int i = t; i < 64 * (F_HID / 8); i += 256) {   // 16B chunks
        int r = i >> 4, c = (i & 15) * 8;
        int rs = row0 + r; if (rs >= N_NODES) rs = N_NODES - 1;
        *(float4*)&sA[r][c] = *(const float4*)(h1b + (size_t)rs * F_HID + c);
    }
    __syncthreads();

    const int ri = (t >> 3) * 2;    // row block (0..62)
    const int cj = (t & 7) * 5;     // col block (0..35)
    float acc[2][5] = {};
    #pragma unroll 8
    for (int k = 0; k < F_HID; ++k) {
        float a0 = __bfloat162float(sA[ri + 0][k]);
        float a1 = __bfloat162float(sA[ri + 1][k]);
        #pragma unroll
        for (int cc = 0; cc < 5; ++cc) {
            float b = sW[k][cj + cc];
            acc[0][cc] = fmaf(a0, b, acc[0][cc]);
            acc[1][cc] = fmaf(a1, b, acc[1][cc]);
        }
    }
    #pragma unroll
    for (int rr = 0; rr < 2; ++rr) {
        int r = row0 + ri + rr;
        if (r >= N_NODES) continue;
        #pragma unroll
        for (int cc = 0; cc < 5; ++cc)
            h2b[(size_t)r * F_OUT + cj + cc] = __float2bfloat16(acc[rr][cc]);
    }
}

// one wave per node: gather-aggregate h2b (40 feats) + bias + log_softmax
__global__ __launch_bounds__(256) void k_agg2_lsm(const __hip_bfloat16* __restrict__ h2b,
                                                  const float* __restrict__ dinv,
                                                  const int* __restrict__ startArr,
                                                  const int* __restrict__ csr,
                                                  const float* __restrict__ b2,
                                                  float* __restrict__ out) {
    int wid  = (blockIdx.x * 256 + threadIdx.x) >> 6;
    int lane = threadIdx.x & 63;
    if (wid >= N_NODES) return;
    int c = wid;
    float dc = dinv[c];
    float acc = 0.f;
    if (lane < F_OUT) acc = dc * dc * __bfloat162float(h2b[(size_t)c * F_OUT + lane]);
    int e = startArr[c], eend = startArr[c + 1];
    while (e < eend) {
        int take = eend - e; if (take > 64) take = 64;
        int r = 0; float w = 0.f;
        if (lane < take) { r = csr[e + lane]; w = dinv[r] * dc; }
        int j = 0;
        for (; j + 3 < take; j += 4) {
            int   r0 = __shfl(r, j),     r1 = __shfl(r, j + 1);
            int   r2 = __shfl(r, j + 2), r3 = __shfl(r, j + 3);
            float w0 = __shfl(w, j),     w1 = __shfl(w, j + 1);
            float w2 = __shfl(w, j + 2), w3 = __shfl(w, j + 3);
            if (lane < F_OUT) {
                float v0 = __bfloat162float(h2b[(size_t)r0 * F_OUT + lane]);
                float v1 = __bfloat162float(h2b[(size_t)r1 * F_OUT + lane]);
                float v2 = __bfloat162float(h2b[(size_t)r2 * F_OUT + lane]);
                float v3 = __bfloat162float(h2b[(size_t)r3 * F_OUT + lane]);
                acc = fmaf(v0, w0, acc);
                acc = fmaf(v1, w1, acc);
                acc = fmaf(v2, w2, acc);
                acc = fmaf(v3, w3, acc);
            }
        }
        for (; j < take; ++j) {
            int   rj = __shfl(r, j);
            float wj = __shfl(w, j);
            if (lane < F_OUT)
                acc = fmaf(__bfloat162float(h2b[(size_t)rj * F_OUT + lane]), wj, acc);
        }
        e += take;
    }
    float v = (lane < F_OUT) ? (acc + b2[lane]) : -INFINITY;
    float m = v;
    #pragma unroll
    for (int o = 32; o > 0; o >>= 1) m = fmaxf(m, __shfl_xor(m, o));
    float ex = (lane < F_OUT) ? expf(v - m) : 0.f;
    float s = ex;
    #pragma unroll
    for (int o = 32; o > 0; o >>= 1) s += __shfl_xor(s, o);
    if (lane < F_OUT) out[(size_t)c * F_OUT + lane] = v - m - logf(s);
}

// ---------------- launch ----------------

extern "C" void kernel_launch(void* const* d_in, const int* in_sizes, int n_in,
                              void* d_out, int out_size, void* d_ws, size_t ws_size,
                              hipStream_t stream) {
    const float* x     = (const float*)d_in[0];
    const int*   ei    = (const int*)d_in[1];
    const float* W1    = (const float*)d_in[2];
    const float* b1    = (const float*)d_in[3];
    const float* W2    = (const float*)d_in[4];
    const float* b2    = (const float*)d_in[5];
    const float* alpha = (const float*)d_in[6];
    float* out = (float*)d_out;

    // workspace layout (elements); bf16 buffers alias dead fp32 regions
    int*   startArr  = (int*)d_ws;                        // 50048 ints
    int*   cursor    = startArr + 50048;                  // 50048
    int*   blockSums = cursor + 50048;                    // 256
    int*   csr       = blockSums + 256;                   // 800000
    float* dinv      = (float*)(csr + N_EDGES);           // 50048 floats
    float* h1region  = dinv + 50048;                      // N*128 fp32 region (25.6 MB)
    __hip_bfloat16* xb  = (__hip_bfloat16*)h1region;      // N*64 bf16 (dead after k_agg1)
    __hip_bfloat16* h1b = (__hip_bfloat16*)h1region;      // N*128 bf16 (overwrites xb)
    float* agg1f     = h1region + (size_t)N_NODES * F_HID; // N*64 fp32 (12.8 MB)
    __hip_bfloat16* h2b = (__hip_bfloat16*)agg1f;         // N*40 bf16 (dead agg1f region)

    const int B = 256;

    hipLaunchKernelGGL(k_zero_cnt, dim3((N_NODES + B - 1) / B), dim3(B), 0, stream, startArr);
    hipLaunchKernelGGL(k_count,    dim3((N_EDGES + B - 1) / B), dim3(B), 0, stream, ei, startArr);
    hipLaunchKernelGGL(k_scanA,    dim3(SCAN_BLOCKS), dim3(B), 0, stream, startArr, blockSums);
    hipLaunchKernelGGL(k_scanB,    dim3(1), dim3(B), 0, stream, blockSums);
    hipLaunchKernelGGL(k_scanC,    dim3(SCAN_BLOCKS), dim3(B), 0, stream, startArr, blockSums, cursor, dinv);
    hipLaunchKernelGGL(k_scatter,  dim3((N_EDGES + B - 1) / B), dim3(B), 0, stream, ei, cursor, csr);

    hipLaunchKernelGGL(k_x2bf,  dim3((N_NODES * 16 + B - 1) / B), dim3(B), 0, stream, x, xb);
    hipLaunchKernelGGL(k_agg1,  dim3((N_NODES * 64 + B - 1) / B), dim3(B), 0, stream, xb, dinv, startArr, csr, agg1f);
    hipLaunchKernelGGL(k_gemm1, dim3((N_NODES + 63) / 64), dim3(B), 0, stream, agg1f, W1, b1, alpha, h1b);
    hipLaunchKernelGGL(k_gemm2, dim3((N_NODES + 63) / 64), dim3(B), 0, stream, h1b, W2, h2b);
    hipLaunchKernelGGL(k_agg2_lsm, dim3((N_NODES * 64 + B - 1) / B), dim3(B), 0, stream,
                       h2b, dinv, startArr, csr, b2, out);
}

// Round 6
// 195.860 us; speedup vs baseline: 5.0697x; 1.0546x over previous
//
#include <hip/hip_runtime.h>
#include <hip/hip_bf16.h>
#include <math.h>

#define N_NODES 50000
#define N_EDGES 800000
#define F_IN    64
#define F_HID   128
#define F_OUT   40
#define SCAN_BLOCKS 196   // ceil(50000/256)
#define SEG_NODES 6250    // 50000 / 8 segments (one per XCD)
#define SCAT_CHUNKS 256   // edge chunks; grid = 8 * SCAT_CHUNKS
#define SCAT_CE 3125      // edges per chunk = 800000 / 256

// ---------------- CSR build ----------------

__global__ void k_zero_cnt(int* __restrict__ cnt) {
    int i = blockIdx.x * blockDim.x + threadIdx.x;
    if (i < N_NODES) cnt[i] = 0;
}

__global__ void k_count(const int* __restrict__ ei, int* __restrict__ cnt) {
    int e = blockIdx.x * blockDim.x + threadIdx.x;
    if (e < N_EDGES) atomicAdd(&cnt[ei[N_EDGES + e]], 1);   // target node
}

// phase A: per-block reduction of 256 counts -> blockSums[b]
__global__ __launch_bounds__(256) void k_scanA(const int* __restrict__ cnt,
                                               int* __restrict__ blockSums) {
    __shared__ int sw[4];
    int i = blockIdx.x * 256 + threadIdx.x;
    int v = (i < N_NODES) ? cnt[i] : 0;
    #pragma unroll
    for (int o = 32; o > 0; o >>= 1) v += __shfl_xor(v, o);
    int lane = threadIdx.x & 63, w = threadIdx.x >> 6;
    if (lane == 0) sw[w] = v;
    __syncthreads();
    if (threadIdx.x == 0) blockSums[blockIdx.x] = sw[0] + sw[1] + sw[2] + sw[3];
}

// phase B: single-block exclusive scan of SCAN_BLOCKS block sums
__global__ __launch_bounds__(256) void k_scanB(int* __restrict__ blockSums) {
    __shared__ int part[256];
    int t = threadIdx.x;
    int v = (t < SCAN_BLOCKS) ? blockSums[t] : 0;
    part[t] = v;
    __syncthreads();
    for (int off = 1; off < 256; off <<= 1) {
        int u = (t >= off) ? part[t - off] : 0;
        __syncthreads();
        part[t] += u;
        __syncthreads();
    }
    if (t < SCAN_BLOCKS) blockSums[t] = part[t] - v;   // exclusive
}

// phase C: intra-block exclusive scan + block offset; emit start/cursor/dinv
__global__ __launch_bounds__(256) void k_scanC(int* __restrict__ startArr,
                                               const int* __restrict__ blockSums,
                                               int* __restrict__ cursor,
                                               float* __restrict__ dinv) {
    __shared__ int part[256];
    int t = threadIdx.x;
    int i = blockIdx.x * 256 + t;
    int v = (i < N_NODES) ? startArr[i] : 0;
    part[t] = v;
    __syncthreads();
    for (int off = 1; off < 256; off <<= 1) {
        int u = (t >= off) ? part[t - off] : 0;
        __syncthreads();
        part[t] += u;
        __syncthreads();
    }
    if (i < N_NODES) {
        int pos = blockSums[blockIdx.x] + part[t] - v;   // exclusive prefix
        startArr[i] = pos;
        cursor[i]   = pos;
        dinv[i]     = rsqrtf((float)v + 1.0f);           // +1 self loop
    }
    if (i == 0) startArr[N_NODES] = N_EDGES;
}

// segmented scatter: block b handles node segment (b&7) over edge chunk (b>>3).
// With round-robin block->XCD dispatch, all writes to a given CSR line come
// from one XCD -> lines accumulate fully in that XCD's L2 (kills the 16x
// write amplification of the unsegmented version).
__global__ __launch_bounds__(256) void k_scatter(const int* __restrict__ ei,
                                                 int* __restrict__ cursor,
                                                 int* __restrict__ csr) {
    int seg = blockIdx.x & 7;
    int lo = seg * SEG_NODES, hi = lo + SEG_NODES;
    int e0 = (blockIdx.x >> 3) * SCAT_CE;
    int e1 = e0 + SCAT_CE; if (e1 > N_EDGES) e1 = N_EDGES;
    for (int e = e0 + threadIdx.x; e < e1; e += 256) {
        int c = ei[N_EDGES + e];
        if (c >= lo && c < hi) {
            int r = ei[e];
            int pos = atomicAdd(&cursor[c], 1);
            csr[pos] = r;
        }
    }
}

// ---------------- x -> bf16 copy ----------------

__global__ void k_x2bf(const float* __restrict__ x, __hip_bfloat16* __restrict__ xb) {
    int i = blockIdx.x * 256 + threadIdx.x;   // over N*16 float4s
    if (i >= N_NODES * 16) return;
    float4 v = ((const float4*)x)[i];
    __hip_bfloat16 o[4] = { __float2bfloat16(v.x), __float2bfloat16(v.y),
                            __float2bfloat16(v.z), __float2bfloat16(v.w) };
    ((ushort4*)xb)[i] = *(const ushort4*)o;
}

// ---------------- layer 1: gather-aggregate X (64 feats, bf16 src) ----------------

__global__ __launch_bounds__(256) void k_agg1(const __hip_bfloat16* __restrict__ xb,
                                              const float* __restrict__ dinv,
                                              const int* __restrict__ startArr,
                                              const int* __restrict__ csr,
                                              float* __restrict__ agg1) {
    int wid  = (blockIdx.x * 256 + threadIdx.x) >> 6;
    int lane = threadIdx.x & 63;
    if (wid >= N_NODES) return;
    int c = wid;
    float dc = dinv[c];
    float acc = dc * dc * __bfloat162float(xb[(size_t)c * F_IN + lane]);   // self loop
    int e = startArr[c], eend = startArr[c + 1];
    while (e < eend) {
        int take = eend - e; if (take > 64) take = 64;
        int r = 0; float w = 0.f;
        if (lane < take) { r = csr[e + lane]; w = dinv[r] * dc; }
        int j = 0;
        for (; j + 3 < take; j += 4) {
            int   r0 = __shfl(r, j),     r1 = __shfl(r, j + 1);
            int   r2 = __shfl(r, j + 2), r3 = __shfl(r, j + 3);
            float w0 = __shfl(w, j),     w1 = __shfl(w, j + 1);
            float w2 = __shfl(w, j + 2), w3 = __shfl(w, j + 3);
            float v0 = __bfloat162float(xb[(size_t)r0 * F_IN + lane]);
            float v1 = __bfloat162float(xb[(size_t)r1 * F_IN + lane]);
            float v2 = __bfloat162float(xb[(size_t)r2 * F_IN + lane]);
            float v3 = __bfloat162float(xb[(size_t)r3 * F_IN + lane]);
            acc = fmaf(v0, w0, acc);
            acc = fmaf(v1, w1, acc);
            acc = fmaf(v2, w2, acc);
            acc = fmaf(v3, w3, acc);
        }
        for (; j < take; ++j) {
            int   rj = __shfl(r, j);
            float wj = __shfl(w, j);
            acc = fmaf(__bfloat162float(xb[(size_t)rj * F_IN + lane]), wj, acc);
        }
        e += take;
    }
    agg1[(size_t)c * F_IN + lane] = acc;
}

// ---------------- layer 1 GEMM: h1b = PReLU(agg1 @ W1 + b1), bf16 out ----------------
// tile: 64 rows x 128 cols; thread = 4 rows x 8 cols register block

__global__ __launch_bounds__(256) void k_gemm1(const float* __restrict__ agg1,
                                               const float* __restrict__ W1,
                                               const float* __restrict__ b1,
                                               const float* __restrict__ alpha,
                                               __hip_bfloat16* __restrict__ h1b) {
    __shared__ float sA[64][F_IN + 1];    // 64x65 fp32, pad kills bank conflicts
    __shared__ float sW[F_IN][F_HID];     // 32 KB
    __shared__ float sb[F_HID];
    int t = threadIdx.x;
    int row0 = blockIdx.x * 64;

    for (int i = t; i < (F_IN * F_HID) / 4; i += 256)
        ((float4*)sW)[i] = ((const float4*)W1)[i];
    if (t < F_HID) sb[t] = b1[t];
    for (int i = t; i < (64 * F_IN) / 4; i += 256) {
        int r = (i * 4) / F_IN, c = (i * 4) & (F_IN - 1);
        int rs = row0 + r; if (rs >= N_NODES) rs = N_NODES - 1;
        float4 v = *(const float4*)(agg1 + (size_t)rs * F_IN + c);
        sA[r][c] = v.x; sA[r][c + 1] = v.y; sA[r][c + 2] = v.z; sA[r][c + 3] = v.w;
    }
    __syncthreads();

    const int ri = (t >> 4) * 4;     // row block (0..60)
    const int cj = (t & 15) * 8;     // col block (0..120)
    float acc[4][8] = {};
    #pragma unroll 4
    for (int k = 0; k < F_IN; ++k) {
        float a0 = sA[ri + 0][k], a1 = sA[ri + 1][k];
        float a2 = sA[ri + 2][k], a3 = sA[ri + 3][k];
        float4 bA = *(const float4*)&sW[k][cj];
        float4 bB = *(const float4*)&sW[k][cj + 4];
        float bv[8] = { bA.x, bA.y, bA.z, bA.w, bB.x, bB.y, bB.z, bB.w };
        #pragma unroll
        for (int cc = 0; cc < 8; ++cc) {
            acc[0][cc] = fmaf(a0, bv[cc], acc[0][cc]);
            acc[1][cc] = fmaf(a1, bv[cc], acc[1][cc]);
            acc[2][cc] = fmaf(a2, bv[cc], acc[2][cc]);
            acc[3][cc] = fmaf(a3, bv[cc], acc[3][cc]);
        }
    }

    const float al = alpha[0];
    #pragma unroll
    for (int rr = 0; rr < 4; ++rr) {
        int r = row0 + ri + rr;
        if (r >= N_NODES) break;
        __hip_bfloat16 o[8];
        #pragma unroll
        for (int cc = 0; cc < 8; ++cc) {
            float v = acc[rr][cc] + sb[cj + cc];
            v = (v >= 0.f) ? v : al * v;
            o[cc] = __float2bfloat16(v);
        }
        *(float4*)(h1b + (size_t)r * F_HID + cj) = *(const float4*)o;   // 16B store
    }
}

// ---------------- layer 2 GEMM: h2b = h1b @ W2, bf16 in/out ----------------
// tile: 64 rows x 40 cols; thread = 2 rows x 5 cols

__global__ __launch_bounds__(256) void k_gemm2(const __hip_bfloat16* __restrict__ h1b,
                                               const float* __restrict__ W2,
                                               __hip_bfloat16* __restrict__ h2b) {
    __shared__ __hip_bfloat16 sA[64][F_HID + 8];   // 64x136 bf16, 16B-aligned rows
    __shared__ float sW[F_HID][F_OUT];             // 20 KB
    int t = threadIdx.x;
    int row0 = blockIdx.x * 64;

    for (int i = t; i < (F_HID * F_OUT) / 4; i += 256)
        ((float4*)sW)[i] = ((const float4*)W2)[i];
    for (int i = t; i < 64 * (F_HID / 8); i += 256) {   // 16B chunks
        int r = i >> 4, c = (i & 15) * 8;
        int rs = row0 + r; if (rs >= N_NODES) rs = N_NODES - 1;
        *(float4*)&sA[r][c] = *(const float4*)(h1b + (size_t)rs * F_HID + c);
    }
    __syncthreads();

    const int ri = (t >> 3) * 2;    // row block (0..62)
    const int cj = (t & 7) * 5;     // col block (0..35)
    float acc[2][5] = {};
    #pragma unroll 8
    for (int k = 0; k < F_HID; ++k) {
        float a0 = __bfloat162float(sA[ri + 0][k]);
        float a1 = __bfloat162float(sA[ri + 1][k]);
        #pragma unroll
        for (int cc = 0; cc < 5; ++cc) {
            float b = sW[k][cj + cc];
            acc[0][cc] = fmaf(a0, b, acc[0][cc]);
            acc[1][cc] = fmaf(a1, b, acc[1][cc]);
        }
    }
    #pragma unroll
    for (int rr = 0; rr < 2; ++rr) {
        int r = row0 + ri + rr;
        if (r >= N_NODES) continue;
        #pragma unroll
        for (int cc = 0; cc < 5; ++cc)
            h2b[(size_t)r * F_OUT + cj + cc] = __float2bfloat16(acc[rr][cc]);
    }
}

// one wave per node: gather-aggregate h2b (40 feats) + bias + log_softmax
__global__ __launch_bounds__(256) void k_agg2_lsm(const __hip_bfloat16* __restrict__ h2b,
                                                  const float* __restrict__ dinv,
                                                  const int* __restrict__ startArr,
                                                  const int* __restrict__ csr,
                                                  const float* __restrict__ b2,
                                                  float* __restrict__ out) {
    int wid  = (blockIdx.x * 256 + threadIdx.x) >> 6;
    int lane = threadIdx.x & 63;
    if (wid >= N_NODES) return;
    int c = wid;
    float dc = dinv[c];
    float acc = 0.f;
    if (lane < F_OUT) acc = dc * dc * __bfloat162float(h2b[(size_t)c * F_OUT + lane]);
    int e = startArr[c], eend = startArr[c + 1];
    while (e < eend) {
        int take = eend - e; if (take > 64) take = 64;
        int r = 0; float w = 0.f;
        if (lane < take) { r = csr[e + lane]; w = dinv[r] * dc; }
        int j = 0;
        for (; j + 3 < take; j += 4) {
            int   r0 = __shfl(r, j),     r1 = __shfl(r, j + 1);
            int   r2 = __shfl(r, j + 2), r3 = __shfl(r, j + 3);
            float w0 = __shfl(w, j),     w1 = __shfl(w, j + 1);
            float w2 = __shfl(w, j + 2), w3 = __shfl(w, j + 3);
            if (lane < F_OUT) {
                float v0 = __bfloat162float(h2b[(size_t)r0 * F_OUT + lane]);
                float v1 = __bfloat162float(h2b[(size_t)r1 * F_OUT + lane]);
                float v2 = __bfloat162float(h2b[(size_t)r2 * F_OUT + lane]);
                float v3 = __bfloat162float(h2b[(size_t)r3 * F_OUT + lane]);
                acc = fmaf(v0, w0, acc);
                acc = fmaf(v1, w1, acc);
                acc = fmaf(v2, w2, acc);
                acc = fmaf(v3, w3, acc);
            }
        }
        for (; j < take; ++j) {
            int   rj = __shfl(r, j);
            float wj = __shfl(w, j);
            if (lane < F_OUT)
                acc = fmaf(__bfloat162float(h2b[(size_t)rj * F_OUT + lane]), wj, acc);
        }
        e += take;
    }
    float v = (lane < F_OUT) ? (acc + b2[lane]) : -INFINITY;
    float m = v;
    #pragma unroll
    for (int o = 32; o > 0; o >>= 1) m = fmaxf(m, __shfl_xor(m, o));
    float ex = (lane < F_OUT) ? expf(v - m) : 0.f;
    float s = ex;
    #pragma unroll
    for (int o = 32; o > 0; o >>= 1) s += __shfl_xor(s, o);
    if (lane < F_OUT) out[(size_t)c * F_OUT + lane] = v - m - logf(s);
}

// ---------------- launch ----------------

extern "C" void kernel_launch(void* const* d_in, const int* in_sizes, int n_in,
                              void* d_out, int out_size, void* d_ws, size_t ws_size,
                              hipStream_t stream) {
    const float* x     = (const float*)d_in[0];
    const int*   ei    = (const int*)d_in[1];
    const float* W1    = (const float*)d_in[2];
    const float* b1    = (const float*)d_in[3];
    const float* W2    = (const float*)d_in[4];
    const float* b2    = (const float*)d_in[5];
    const float* alpha = (const float*)d_in[6];
    float* out = (float*)d_out;

    // workspace layout (elements); bf16 buffers alias dead fp32 regions
    int*   startArr  = (int*)d_ws;                        // 50048 ints
    int*   cursor    = startArr + 50048;                  // 50048
    int*   blockSums = cursor + 50048;                    // 256
    int*   csr       = blockSums + 256;                   // 800000
    float* dinv      = (float*)(csr + N_EDGES);           // 50048 floats
    float* h1region  = dinv + 50048;                      // N*128 fp32 region (25.6 MB)
    __hip_bfloat16* xb  = (__hip_bfloat16*)h1region;      // N*64 bf16 (dead after k_agg1)
    __hip_bfloat16* h1b = (__hip_bfloat16*)h1region;      // N*128 bf16 (overwrites xb)
    float* agg1f     = h1region + (size_t)N_NODES * F_HID; // N*64 fp32 (12.8 MB)
    __hip_bfloat16* h2b = (__hip_bfloat16*)agg1f;         // N*40 bf16 (dead agg1f region)

    const int B = 256;

    hipLaunchKernelGGL(k_zero_cnt, dim3((N_NODES + B - 1) / B), dim3(B), 0, stream, startArr);
    hipLaunchKernelGGL(k_count,    dim3((N_EDGES + B - 1) / B), dim3(B), 0, stream, ei, startArr);
    hipLaunchKernelGGL(k_scanA,    dim3(SCAN_BLOCKS), dim3(B), 0, stream, startArr, blockSums);
    hipLaunchKernelGGL(k_scanB,    dim3(1), dim3(B), 0, stream, blockSums);
    hipLaunchKernelGGL(k_scanC,    dim3(SCAN_BLOCKS), dim3(B), 0, stream, startArr, blockSums, cursor, dinv);
    hipLaunchKernelGGL(k_scatter,  dim3(8 * SCAT_CHUNKS), dim3(B), 0, stream, ei, cursor, csr);

    hipLaunchKernelGGL(k_x2bf,  dim3((N_NODES * 16 + B - 1) / B), dim3(B), 0, stream, x, xb);
    hipLaunchKernelGGL(k_agg1,  dim3((N_NODES * 64 + B - 1) / B), dim3(B), 0, stream, xb, dinv, startArr, csr, agg1f);
    hipLaunchKernelGGL(k_gemm1, dim3((N_NODES + 63) / 64), dim3(B), 0, stream, agg1f, W1, b1, alpha, h1b);
    hipLaunchKernelGGL(k_gemm2, dim3((N_NODES + 63) / 64), dim3(B), 0, stream, h1b, W2, h2b);
    hipLaunchKernelGGL(k_agg2_lsm, dim3((N_NODES * 64 + B - 1) / B), dim3(B), 0, stream,
                       h2b, dinv, startArr, csr, b2, out);
}

// Round 7
// 184.235 us; speedup vs baseline: 5.3895x; 1.0631x over previous
//
#include <hip/hip_runtime.h>
#include <hip/hip_bf16.h>
#include <math.h>

#define N_NODES 50000
#define N_EDGES 800000
#define F_IN    64
#define F_HID   128
#define F_OUT   40
#define H2_STR  64        // padded h2b row stride (bf16)
#define SCAN_BLOCKS 196   // ceil(50000/256)
#define SEG_NODES 6250    // 50000 / 8 segments (one per XCD)
#define SCAT_CHUNKS 256   // edge chunks; grid = 8 * SCAT_CHUNKS
#define SCAT_CE 3125      // edges per chunk = 800000 / 256

typedef unsigned short ushort8_t __attribute__((ext_vector_type(8)));

__device__ __forceinline__ float bf2f(unsigned short u) {
    union { float f; unsigned int i; } x; x.i = ((unsigned int)u) << 16; return x.f;
}

// ---------------- fused: x->bf16 + zero counters ----------------

__global__ void k_x2bf_zero(const float* __restrict__ x, __hip_bfloat16* __restrict__ xb,
                            int* __restrict__ cnt) {
    int i = blockIdx.x * 256 + threadIdx.x;   // over N*16 float4s
    if (i < N_NODES) cnt[i] = 0;
    if (i >= N_NODES * 16) return;
    float4 v = ((const float4*)x)[i];
    __hip_bfloat16 o[4] = { __float2bfloat16(v.x), __float2bfloat16(v.y),
                            __float2bfloat16(v.z), __float2bfloat16(v.w) };
    ((ushort4*)xb)[i] = *(const ushort4*)o;
}

__global__ void k_count(const int* __restrict__ ei, int* __restrict__ cnt) {
    int e = blockIdx.x * blockDim.x + threadIdx.x;
    if (e < N_EDGES) atomicAdd(&cnt[ei[N_EDGES + e]], 1);   // target node
}

// phase A: per-block reduction of 256 counts -> blockSums[b]
__global__ __launch_bounds__(256) void k_scanA(const int* __restrict__ cnt,
                                               int* __restrict__ blockSums) {
    __shared__ int sw[4];
    int i = blockIdx.x * 256 + threadIdx.x;
    int v = (i < N_NODES) ? cnt[i] : 0;
    #pragma unroll
    for (int o = 32; o > 0; o >>= 1) v += __shfl_xor(v, o);
    int lane = threadIdx.x & 63, w = threadIdx.x >> 6;
    if (lane == 0) sw[w] = v;
    __syncthreads();
    if (threadIdx.x == 0) blockSums[blockIdx.x] = sw[0] + sw[1] + sw[2] + sw[3];
}

// phase B: single-block exclusive scan of SCAN_BLOCKS block sums
__global__ __launch_bounds__(256) void k_scanB(int* __restrict__ blockSums) {
    __shared__ int part[256];
    int t = threadIdx.x;
    int v = (t < SCAN_BLOCKS) ? blockSums[t] : 0;
    part[t] = v;
    __syncthreads();
    for (int off = 1; off < 256; off <<= 1) {
        int u = (t >= off) ? part[t - off] : 0;
        __syncthreads();
        part[t] += u;
        __syncthreads();
    }
    if (t < SCAN_BLOCKS) blockSums[t] = part[t] - v;   // exclusive
}

// phase C: intra-block exclusive scan + block offset; emit start/cursor/dinv
__global__ __launch_bounds__(256) void k_scanC(int* __restrict__ startArr,
                                               const int* __restrict__ blockSums,
                                               int* __restrict__ cursor,
                                               float* __restrict__ dinv) {
    __shared__ int part[256];
    int t = threadIdx.x;
    int i = blockIdx.x * 256 + t;
    int v = (i < N_NODES) ? startArr[i] : 0;
    part[t] = v;
    __syncthreads();
    for (int off = 1; off < 256; off <<= 1) {
        int u = (t >= off) ? part[t - off] : 0;
        __syncthreads();
        part[t] += u;
        __syncthreads();
    }
    if (i < N_NODES) {
        int pos = blockSums[blockIdx.x] + part[t] - v;   // exclusive prefix
        startArr[i] = pos;
        cursor[i]   = pos;
        dinv[i]     = rsqrtf((float)v + 1.0f);           // +1 self loop
    }
    if (i == 0) startArr[N_NODES] = N_EDGES;
}

// segmented scatter (XCD write locality via blockIdx%8 round-robin dispatch)
__global__ __launch_bounds__(256) void k_scatter(const int* __restrict__ ei,
                                                 int* __restrict__ cursor,
                                                 int* __restrict__ csr) {
    int seg = blockIdx.x & 7;
    int lo = seg * SEG_NODES, hi = lo + SEG_NODES;
    int e0 = (blockIdx.x >> 3) * SCAT_CE;
    int e1 = e0 + SCAT_CE; if (e1 > N_EDGES) e1 = N_EDGES;
    for (int e = e0 + threadIdx.x; e < e1; e += 256) {
        int c = ei[N_EDGES + e];
        if (c >= lo && c < hi) {
            int r = ei[e];
            int pos = atomicAdd(&cursor[c], 1);
            csr[pos] = r;
        }
    }
}

// ---------------- layer 1 gather: wave = node; 8 rows/instr, 16B/lane ----------------
// lane = (o,s): o = row-in-group (0..7), s = 8-feature chunk (0..7)

__global__ __launch_bounds__(256) void k_agg1(const __hip_bfloat16* __restrict__ xb,
                                              const float* __restrict__ dinv,
                                              const int* __restrict__ startArr,
                                              const int* __restrict__ csr,
                                              float* __restrict__ agg1) {
    int wid  = (blockIdx.x * 256 + threadIdx.x) >> 6;
    int lane = threadIdx.x & 63;
    if (wid >= N_NODES) return;
    const int o = lane >> 3, s = lane & 7;
    const int c = wid;
    const float dc = dinv[c];
    float acc[8] = {};

    if (o == 0) {   // self loop
        float w = dc * dc;
        ushort8_t v = *(const ushort8_t*)(xb + (size_t)c * F_IN + s * 8);
        #pragma unroll
        for (int k = 0; k < 8; ++k) acc[k] = fmaf(bf2f(v[k]), w, acc[k]);
    }

    int e = startArr[c], eend = startArr[c + 1];
    while (e < eend) {
        int take = eend - e; if (take > 64) take = 64;
        int r = 0; float w = 0.f;   // lanes >= take keep w=0 -> masked
        if (lane < take) { r = csr[e + lane]; w = dinv[r] * dc; }
        for (int j = 0; j < take; j += 16) {
            int ia = j + o;      ia = ia > 63 ? 63 : ia;
            int ib = j + 8 + o;  ib = ib > 63 ? 63 : ib;
            int   ra = __shfl(r, ia), rb = __shfl(r, ib);
            float wa = __shfl(w, ia), wb = __shfl(w, ib);
            ushort8_t va = *(const ushort8_t*)(xb + (size_t)ra * F_IN + s * 8);
            ushort8_t vb = *(const ushort8_t*)(xb + (size_t)rb * F_IN + s * 8);
            #pragma unroll
            for (int k = 0; k < 8; ++k) acc[k] = fmaf(bf2f(va[k]), wa, acc[k]);
            #pragma unroll
            for (int k = 0; k < 8; ++k) acc[k] = fmaf(bf2f(vb[k]), wb, acc[k]);
        }
        e += take;
    }

    #pragma unroll
    for (int k = 0; k < 8; ++k) {
        acc[k] += __shfl_xor(acc[k], 8);
        acc[k] += __shfl_xor(acc[k], 16);
        acc[k] += __shfl_xor(acc[k], 32);
    }
    if (o == 0) {
        float4 a = { acc[0], acc[1], acc[2], acc[3] };
        float4 b = { acc[4], acc[5], acc[6], acc[7] };
        *(float4*)(agg1 + (size_t)c * F_IN + s * 8)     = a;
        *(float4*)(agg1 + (size_t)c * F_IN + s * 8 + 4) = b;
    }
}

// ---------------- layer 1 GEMM: h1b = PReLU(agg1 @ W1 + b1), bf16 out ----------------

__global__ __launch_bounds__(256) void k_gemm1(const float* __restrict__ agg1,
                                               const float* __restrict__ W1,
                                               const float* __restrict__ b1,
                                               const float* __restrict__ alpha,
                                               __hip_bfloat16* __restrict__ h1b) {
    __shared__ float sA[64][F_IN + 1];
    __shared__ float sW[F_IN][F_HID];
    __shared__ float sb[F_HID];
    int t = threadIdx.x;
    int row0 = blockIdx.x * 64;

    for (int i = t; i < (F_IN * F_HID) / 4; i += 256)
        ((float4*)sW)[i] = ((const float4*)W1)[i];
    if (t < F_HID) sb[t] = b1[t];
    for (int i = t; i < (64 * F_IN) / 4; i += 256) {
        int r = (i * 4) / F_IN, c = (i * 4) & (F_IN - 1);
        int rs = row0 + r; if (rs >= N_NODES) rs = N_NODES - 1;
        float4 v = *(const float4*)(agg1 + (size_t)rs * F_IN + c);
        sA[r][c] = v.x; sA[r][c + 1] = v.y; sA[r][c + 2] = v.z; sA[r][c + 3] = v.w;
    }
    __syncthreads();

    const int ri = (t >> 4) * 4;
    const int cj = (t & 15) * 8;
    float acc[4][8] = {};
    #pragma unroll 4
    for (int k = 0; k < F_IN; ++k) {
        float a0 = sA[ri + 0][k], a1 = sA[ri + 1][k];
        float a2 = sA[ri + 2][k], a3 = sA[ri + 3][k];
        float4 bA = *(const float4*)&sW[k][cj];
        float4 bB = *(const float4*)&sW[k][cj + 4];
        float bv[8] = { bA.x, bA.y, bA.z, bA.w, bB.x, bB.y, bB.z, bB.w };
        #pragma unroll
        for (int cc = 0; cc < 8; ++cc) {
            acc[0][cc] = fmaf(a0, bv[cc], acc[0][cc]);
            acc[1][cc] = fmaf(a1, bv[cc], acc[1][cc]);
            acc[2][cc] = fmaf(a2, bv[cc], acc[2][cc]);
            acc[3][cc] = fmaf(a3, bv[cc], acc[3][cc]);
        }
    }

    const float al = alpha[0];
    #pragma unroll
    for (int rr = 0; rr < 4; ++rr) {
        int r = row0 + ri + rr;
        if (r >= N_NODES) break;
        __hip_bfloat16 o[8];
        #pragma unroll
        for (int cc = 0; cc < 8; ++cc) {
            float v = acc[rr][cc] + sb[cj + cc];
            v = (v >= 0.f) ? v : al * v;
            o[cc] = __float2bfloat16(v);
        }
        *(float4*)(h1b + (size_t)r * F_HID + cj) = *(const float4*)o;
    }
}

// ---------------- layer 2 GEMM: h2b(stride 64, zero-padded) = h1b @ W2 ----------------

__global__ __launch_bounds__(256) void k_gemm2(const __hip_bfloat16* __restrict__ h1b,
                                               const float* __restrict__ W2,
                                               __hip_bfloat16* __restrict__ h2b) {
    __shared__ __hip_bfloat16 sA[64][F_HID + 8];
    __shared__ float sW[F_HID][F_OUT];
    int t = threadIdx.x;
    int row0 = blockIdx.x * 64;

    for (int i = t; i < (F_HID * F_OUT) / 4; i += 256)
        ((float4*)sW)[i] = ((const float4*)W2)[i];
    for (int i = t; i < 64 * (F_HID / 8); i += 256) {
        int r = i >> 4, c = (i & 15) * 8;
        int rs = row0 + r; if (rs >= N_NODES) rs = N_NODES - 1;
        *(float4*)&sA[r][c] = *(const float4*)(h1b + (size_t)rs * F_HID + c);
    }
    __syncthreads();

    const int ri = (t >> 3) * 2;
    const int cj = (t & 7) * 5;
    float acc[2][5] = {};
    #pragma unroll 8
    for (int k = 0; k < F_HID; ++k) {
        float a0 = __bfloat162float(sA[ri + 0][k]);
        float a1 = __bfloat162float(sA[ri + 1][k]);
        #pragma unroll
        for (int cc = 0; cc < 5; ++cc) {
            float b = sW[k][cj + cc];
            acc[0][cc] = fmaf(a0, b, acc[0][cc]);
            acc[1][cc] = fmaf(a1, b, acc[1][cc]);
        }
    }
    #pragma unroll
    for (int rr = 0; rr < 2; ++rr) {
        int r = row0 + ri + rr;
        if (r >= N_NODES) continue;
        #pragma unroll
        for (int cc = 0; cc < 5; ++cc)
            h2b[(size_t)r * H2_STR + cj + cc] = __float2bfloat16(acc[rr][cc]);
    }
    // zero the padding cols 40..63 so the gather can skip masking
    const __hip_bfloat16 z = __float2bfloat16(0.f);
    for (int i = t; i < 64 * (H2_STR - F_OUT); i += 256) {
        int r = row0 + i / (H2_STR - F_OUT);
        int cc = F_OUT + i % (H2_STR - F_OUT);
        if (r < N_NODES) h2b[(size_t)r * H2_STR + cc] = z;
    }
}

// ---------------- layer 2 gather + bias + log_softmax ----------------
// same (o,s) scheme; feats s*8+k, valid < 40; h2b stride 64, padding = 0

__global__ __launch_bounds__(256) void k_agg2_lsm(const __hip_bfloat16* __restrict__ h2b,
                                                  const float* __restrict__ dinv,
                                                  const int* __restrict__ startArr,
                                                  const int* __restrict__ csr,
                                                  const float* __restrict__ b2,
                                                  float* __restrict__ out) {
    int wid  = (blockIdx.x * 256 + threadIdx.x) >> 6;
    int lane = threadIdx.x & 63;
    if (wid >= N_NODES) return;
    const int o = lane >> 3, s = lane & 7;
    const int c = wid;
    const float dc = dinv[c];
    float acc[8] = {};

    if (o == 0) {   // self loop (padding cols are zero)
        float w = dc * dc;
        ushort8_t v = *(const ushort8_t*)(h2b + (size_t)c * H2_STR + s * 8);
        #pragma unroll
        for (int k = 0; k < 8; ++k) acc[k] = fmaf(bf2f(v[k]), w, acc[k]);
    }

    int e = startArr[c], eend = startArr[c + 1];
    while (e < eend) {
        int take = eend - e; if (take > 64) take = 64;
        int r = 0; float w = 0.f;
        if (lane < take) { r = csr[e + lane]; w = dinv[r] * dc; }
        for (int j = 0; j < take; j += 16) {
            int ia = j + o;      ia = ia > 63 ? 63 : ia;
            int ib = j + 8 + o;  ib = ib > 63 ? 63 : ib;
            int   ra = __shfl(r, ia), rb = __shfl(r, ib);
            float wa = __shfl(w, ia), wb = __shfl(w, ib);
            ushort8_t va = *(const ushort8_t*)(h2b + (size_t)ra * H2_STR + s * 8);
            ushort8_t vb = *(const ushort8_t*)(h2b + (size_t)rb * H2_STR + s * 8);
            #pragma unroll
            for (int k = 0; k < 8; ++k) acc[k] = fmaf(bf2f(va[k]), wa, acc[k]);
            #pragma unroll
            for (int k = 0; k < 8; ++k) acc[k] = fmaf(bf2f(vb[k]), wb, acc[k]);
        }
        e += take;
    }

    #pragma unroll
    for (int k = 0; k < 8; ++k) {
        acc[k] += __shfl_xor(acc[k], 8);
        acc[k] += __shfl_xor(acc[k], 16);
        acc[k] += __shfl_xor(acc[k], 32);
    }

    // bias + log_softmax in (o,s) layout; feats f = s*8+k valid iff f < 40 (s < 5)
    float vloc[8];
    float m = -INFINITY;
    if (s < 5) {
        float4 p = *(const float4*)(b2 + s * 8);
        float4 q = *(const float4*)(b2 + s * 8 + 4);
        float bb[8] = { p.x, p.y, p.z, p.w, q.x, q.y, q.z, q.w };
        #pragma unroll
        for (int k = 0; k < 8; ++k) { vloc[k] = acc[k] + bb[k]; m = fmaxf(m, vloc[k]); }
    } else {
        #pragma unroll
        for (int k = 0; k < 8; ++k) vloc[k] = -INFINITY;
    }
    m = fmaxf(m, __shfl_xor(m, 1));
    m = fmaxf(m, __shfl_xor(m, 2));
    m = fmaxf(m, __shfl_xor(m, 4));
    float sum = 0.f;
    if (s < 5) {
        #pragma unroll
        for (int k = 0; k < 8; ++k) sum += expf(vloc[k] - m);
    }
    sum += __shfl_xor(sum, 1);
    sum += __shfl_xor(sum, 2);
    sum += __shfl_xor(sum, 4);
    float ls = m + logf(sum);

    if (o == 0 && s < 5) {
        float4 a = { vloc[0] - ls, vloc[1] - ls, vloc[2] - ls, vloc[3] - ls };
        float4 b = { vloc[4] - ls, vloc[5] - ls, vloc[6] - ls, vloc[7] - ls };
        *(float4*)(out + (size_t)c * F_OUT + s * 8)     = a;
        *(float4*)(out + (size_t)c * F_OUT + s * 8 + 4) = b;
    }
}

// ---------------- launch ----------------

extern "C" void kernel_launch(void* const* d_in, const int* in_sizes, int n_in,
                              void* d_out, int out_size, void* d_ws, size_t ws_size,
                              hipStream_t stream) {
    const float* x     = (const float*)d_in[0];
    const int*   ei    = (const int*)d_in[1];
    const float* W1    = (const float*)d_in[2];
    const float* b1    = (const float*)d_in[3];
    const float* W2    = (const float*)d_in[4];
    const float* b2    = (const float*)d_in[5];
    const float* alpha = (const float*)d_in[6];
    float* out = (float*)d_out;

    // workspace layout (elements); bf16 buffers alias dead fp32 regions
    int*   startArr  = (int*)d_ws;                        // 50048 ints
    int*   cursor    = startArr + 50048;                  // 50048
    int*   blockSums = cursor + 50048;                    // 256
    int*   csr       = blockSums + 256;                   // 800000
    float* dinv      = (float*)(csr + N_EDGES);           // 50048 floats
    float* h1region  = dinv + 50048;                      // N*128 fp32 region (25.6 MB)
    __hip_bfloat16* xb  = (__hip_bfloat16*)h1region;      // N*64 bf16 (dead after k_agg1)
    __hip_bfloat16* h1b = (__hip_bfloat16*)h1region;      // N*128 bf16 (overwrites xb)
    float* agg1f     = h1region + (size_t)N_NODES * F_HID; // N*64 fp32 (12.8 MB)
    __hip_bfloat16* h2b = (__hip_bfloat16*)agg1f;         // N*64 bf16 padded (dead agg1f region)

    const int B = 256;

    hipLaunchKernelGGL(k_x2bf_zero, dim3((N_NODES * 16 + B - 1) / B), dim3(B), 0, stream, x, xb, startArr);
    hipLaunchKernelGGL(k_count,     dim3((N_EDGES + B - 1) / B), dim3(B), 0, stream, ei, startArr);
    hipLaunchKernelGGL(k_scanA,     dim3(SCAN_BLOCKS), dim3(B), 0, stream, startArr, blockSums);
    hipLaunchKernelGGL(k_scanB,     dim3(1), dim3(B), 0, stream, blockSums);
    hipLaunchKernelGGL(k_scanC,     dim3(SCAN_BLOCKS), dim3(B), 0, stream, startArr, blockSums, cursor, dinv);
    hipLaunchKernelGGL(k_scatter,   dim3(8 * SCAT_CHUNKS), dim3(B), 0, stream, ei, cursor, csr);

    hipLaunchKernelGGL(k_agg1,  dim3((N_NODES * 64 + B - 1) / B), dim3(B), 0, stream, xb, dinv, startArr, csr, agg1f);
    hipLaunchKernelGGL(k_gemm1, dim3((N_NODES + 63) / 64), dim3(B), 0, stream, agg1f, W1, b1, alpha, h1b);
    hipLaunchKernelGGL(k_gemm2, dim3((N_NODES + 63) / 64), dim3(B), 0, stream, h1b, W2, h2b);
    hipLaunchKernelGGL(k_agg2_lsm, dim3((N_NODES * 64 + B - 1) / B), dim3(B), 0, stream,
                       h2b, dinv, startArr, csr, b2, out);
}

// Round 8
// 174.690 us; speedup vs baseline: 5.6840x; 1.0546x over previous
//
#include <hip/hip_runtime.h>
#include <hip/hip_bf16.h>
#include <math.h>

#define N_NODES 50000
#define N_EDGES 800000
#define F_IN    64
#define F_HID   128
#define F_OUT   40
#define H2_STR  64        // padded h2b row stride (bf16)
#define SCAN_BLOCKS 196   // ceil(50000/256)
#define SEG_NODES 6250    // 50000 / 8 segments (one per XCD)
#define SCAT_CHUNKS 256   // edge chunks; grid = 8 * SCAT_CHUNKS
#define SCAT_CE 3125      // edges per chunk = 800000 / 256

typedef unsigned short ushort8_t __attribute__((ext_vector_type(8)));

__device__ __forceinline__ float bf2f(unsigned short u) {
    union { float f; unsigned int i; } x; x.i = ((unsigned int)u) << 16; return x.f;
}
__device__ __forceinline__ unsigned short f2bf(float f) {
    union { __hip_bfloat16 h; unsigned short u; } x; x.h = __float2bfloat16(f); return x.u;
}

// ---------------- fused: x->bf16 + zero counters ----------------

__global__ void k_x2bf_zero(const float* __restrict__ x, __hip_bfloat16* __restrict__ xb,
                            int* __restrict__ cnt) {
    int i = blockIdx.x * 256 + threadIdx.x;   // over N*16 float4s
    if (i < N_NODES) cnt[i] = 0;
    if (i >= N_NODES * 16) return;
    float4 v = ((const float4*)x)[i];
    __hip_bfloat16 o[4] = { __float2bfloat16(v.x), __float2bfloat16(v.y),
                            __float2bfloat16(v.z), __float2bfloat16(v.w) };
    ((ushort4*)xb)[i] = *(const ushort4*)o;
}

__global__ void k_count(const int* __restrict__ ei, int* __restrict__ cnt) {
    int e = blockIdx.x * blockDim.x + threadIdx.x;
    if (e < N_EDGES) atomicAdd(&cnt[ei[N_EDGES + e]], 1);   // target node
}

// phase A: per-block reduction of 256 counts -> blockSums[b]
__global__ __launch_bounds__(256) void k_scanA(const int* __restrict__ cnt,
                                               int* __restrict__ blockSums) {
    __shared__ int sw[4];
    int i = blockIdx.x * 256 + threadIdx.x;
    int v = (i < N_NODES) ? cnt[i] : 0;
    #pragma unroll
    for (int o = 32; o > 0; o >>= 1) v += __shfl_xor(v, o);
    int lane = threadIdx.x & 63, w = threadIdx.x >> 6;
    if (lane == 0) sw[w] = v;
    __syncthreads();
    if (threadIdx.x == 0) blockSums[blockIdx.x] = sw[0] + sw[1] + sw[2] + sw[3];
}

// phase C (fused with B): every block redundantly scans the 196 block sums,
// then does its intra-block exclusive scan; emits start/cursor/dinv
__global__ __launch_bounds__(256) void k_scanC(int* __restrict__ startArr,
                                               const int* __restrict__ blockSums,
                                               int* __restrict__ cursor,
                                               float* __restrict__ dinv) {
    __shared__ int sbs[256];
    __shared__ int part[256];
    int t = threadIdx.x;
    int bv = (t < SCAN_BLOCKS) ? blockSums[t] : 0;
    sbs[t] = bv;
    __syncthreads();
    for (int off = 1; off < 256; off <<= 1) {
        int u = (t >= off) ? sbs[t - off] : 0;
        __syncthreads();
        sbs[t] += u;
        __syncthreads();
    }
    int blockOff = (blockIdx.x == 0) ? 0 : sbs[blockIdx.x - 1];

    int i = blockIdx.x * 256 + t;
    int v = (i < N_NODES) ? startArr[i] : 0;
    part[t] = v;
    __syncthreads();
    for (int off = 1; off < 256; off <<= 1) {
        int u = (t >= off) ? part[t - off] : 0;
        __syncthreads();
        part[t] += u;
        __syncthreads();
    }
    if (i < N_NODES) {
        int pos = blockOff + part[t] - v;   // exclusive prefix
        startArr[i] = pos;
        cursor[i]   = pos;
        dinv[i]     = rsqrtf((float)v + 1.0f);           // +1 self loop
    }
    if (i == 0) startArr[N_NODES] = N_EDGES;
}

// segmented scatter (XCD write locality via blockIdx%8 round-robin dispatch)
__global__ __launch_bounds__(256) void k_scatter(const int* __restrict__ ei,
                                                 int* __restrict__ cursor,
                                                 int* __restrict__ csr) {
    int seg = blockIdx.x & 7;
    int lo = seg * SEG_NODES, hi = lo + SEG_NODES;
    int e0 = (blockIdx.x >> 3) * SCAT_CE;
    int e1 = e0 + SCAT_CE; if (e1 > N_EDGES) e1 = N_EDGES;
    for (int e = e0 + threadIdx.x; e < e1; e += 256) {
        int c = ei[N_EDGES + e];
        if (c >= lo && c < hi) {
            int r = ei[e];
            int pos = atomicAdd(&cursor[c], 1);
            csr[pos] = r;
        }
    }
}

// ---------------- layer 1 gather: wave = node; 8 rows/instr, 16B/lane ----------------
// lane = (o,s): o = row-in-group (0..7), s = 8-feature chunk (0..7); bf16 out

__global__ __launch_bounds__(256) void k_agg1(const __hip_bfloat16* __restrict__ xb,
                                              const float* __restrict__ dinv,
                                              const int* __restrict__ startArr,
                                              const int* __restrict__ csr,
                                              __hip_bfloat16* __restrict__ agg1b) {
    int wid  = (blockIdx.x * 256 + threadIdx.x) >> 6;
    int lane = threadIdx.x & 63;
    if (wid >= N_NODES) return;
    const int o = lane >> 3, s = lane & 7;
    const int c = wid;
    const float dc = dinv[c];
    float acc[8] = {};

    if (o == 0) {   // self loop
        float w = dc * dc;
        ushort8_t v = *(const ushort8_t*)(xb + (size_t)c * F_IN + s * 8);
        #pragma unroll
        for (int k = 0; k < 8; ++k) acc[k] = fmaf(bf2f(v[k]), w, acc[k]);
    }

    int e = startArr[c], eend = startArr[c + 1];
    while (e < eend) {
        int take = eend - e; if (take > 64) take = 64;
        int r = 0; float w = 0.f;   // lanes >= take keep w=0 -> masked
        if (lane < take) { r = csr[e + lane]; w = dinv[r] * dc; }
        for (int j = 0; j < take; j += 16) {
            int ia = j + o;      ia = ia > 63 ? 63 : ia;
            int ib = j + 8 + o;  ib = ib > 63 ? 63 : ib;
            int   ra = __shfl(r, ia), rb = __shfl(r, ib);
            float wa = __shfl(w, ia), wb = __shfl(w, ib);
            ushort8_t va = *(const ushort8_t*)(xb + (size_t)ra * F_IN + s * 8);
            ushort8_t vb = *(const ushort8_t*)(xb + (size_t)rb * F_IN + s * 8);
            #pragma unroll
            for (int k = 0; k < 8; ++k) acc[k] = fmaf(bf2f(va[k]), wa, acc[k]);
            #pragma unroll
            for (int k = 0; k < 8; ++k) acc[k] = fmaf(bf2f(vb[k]), wb, acc[k]);
        }
        e += take;
    }

    #pragma unroll
    for (int k = 0; k < 8; ++k) {
        acc[k] += __shfl_xor(acc[k], 8);
        acc[k] += __shfl_xor(acc[k], 16);
        acc[k] += __shfl_xor(acc[k], 32);
    }
    if (o == 0) {
        ushort8_t o8;
        #pragma unroll
        for (int k = 0; k < 8; ++k) o8[k] = f2bf(acc[k]);
        *(ushort8_t*)(agg1b + (size_t)c * F_IN + s * 8) = o8;
    }
}

// ---------------- fused GEMM: h2b = (PReLU(agg1b@W1+b1)) @ W2, all in one tile ----
// stage 1: 64x64 @ 64x128 -> sH (bf16); stage 2: 64x128 @ 128x40 -> h2b (padded)

__global__ __launch_bounds__(256) void k_gemm12(const __hip_bfloat16* __restrict__ agg1b,
                                                const float* __restrict__ W1,
                                                const float* __restrict__ b1,
                                                const float* __restrict__ alpha,
                                                const float* __restrict__ W2,
                                                __hip_bfloat16* __restrict__ h2b) {
    __shared__ float sW1[F_IN][F_HID];              // 32 KB
    __shared__ float sW2[F_HID][F_OUT];             // 20 KB
    __shared__ float sb[F_HID];
    __shared__ __hip_bfloat16 sA[64][F_IN + 8];     // 9 KB
    __shared__ __hip_bfloat16 sH[64][F_HID + 8];    // 17 KB
    int t = threadIdx.x;
    int row0 = blockIdx.x * 64;

    for (int i = t; i < (F_IN * F_HID) / 4; i += 256)
        ((float4*)sW1)[i] = ((const float4*)W1)[i];
    for (int i = t; i < (F_HID * F_OUT) / 4; i += 256)
        ((float4*)sW2)[i] = ((const float4*)W2)[i];
    if (t < F_HID) sb[t] = b1[t];
    for (int i = t; i < 64 * (F_IN / 8); i += 256) {    // 16B chunks: 512 total
        int r = i >> 3, c = (i & 7) * 8;
        int rs = row0 + r; if (rs >= N_NODES) rs = N_NODES - 1;
        *(float4*)&sA[r][c] = *(const float4*)(agg1b + (size_t)rs * F_IN + c);
    }
    __syncthreads();

    // stage 1: thread = 4 rows x 8 cols
    {
        const int ri = (t >> 4) * 4;
        const int cj = (t & 15) * 8;
        float acc[4][8] = {};
        #pragma unroll 4
        for (int k = 0; k < F_IN; ++k) {
            float a0 = bf2f(*(const unsigned short*)&sA[ri + 0][k]);
            float a1 = bf2f(*(const unsigned short*)&sA[ri + 1][k]);
            float a2 = bf2f(*(const unsigned short*)&sA[ri + 2][k]);
            float a3 = bf2f(*(const unsigned short*)&sA[ri + 3][k]);
            float4 bA = *(const float4*)&sW1[k][cj];
            float4 bB = *(const float4*)&sW1[k][cj + 4];
            float bv[8] = { bA.x, bA.y, bA.z, bA.w, bB.x, bB.y, bB.z, bB.w };
            #pragma unroll
            for (int cc = 0; cc < 8; ++cc) {
                acc[0][cc] = fmaf(a0, bv[cc], acc[0][cc]);
                acc[1][cc] = fmaf(a1, bv[cc], acc[1][cc]);
                acc[2][cc] = fmaf(a2, bv[cc], acc[2][cc]);
                acc[3][cc] = fmaf(a3, bv[cc], acc[3][cc]);
            }
        }
        const float al = alpha[0];
        #pragma unroll
        for (int rr = 0; rr < 4; ++rr) {
            #pragma unroll
            for (int cc = 0; cc < 8; ++cc) {
                float v = acc[rr][cc] + sb[cj + cc];
                v = (v >= 0.f) ? v : al * v;
                *(unsigned short*)&sH[ri + rr][cj + cc] = f2bf(v);
            }
        }
    }
    __syncthreads();

    // stage 2: thread = 2 rows x 5 cols
    {
        const int ri = (t >> 3) * 2;
        const int cj = (t & 7) * 5;
        float acc[2][5] = {};
        #pragma unroll 8
        for (int k = 0; k < F_HID; ++k) {
            float a0 = bf2f(*(const unsigned short*)&sH[ri + 0][k]);
            float a1 = bf2f(*(const unsigned short*)&sH[ri + 1][k]);
            #pragma unroll
            for (int cc = 0; cc < 5; ++cc) {
                float b = sW2[k][cj + cc];
                acc[0][cc] = fmaf(a0, b, acc[0][cc]);
                acc[1][cc] = fmaf(a1, b, acc[1][cc]);
            }
        }
        #pragma unroll
        for (int rr = 0; rr < 2; ++rr) {
            int r = row0 + ri + rr;
            if (r >= N_NODES) continue;
            #pragma unroll
            for (int cc = 0; cc < 5; ++cc)
                h2b[(size_t)r * H2_STR + cj + cc] = __float2bfloat16(acc[rr][cc]);
        }
    }
    // zero padding cols 40..63 (3 x 16B chunks per row)
    {
        float4 z = { 0.f, 0.f, 0.f, 0.f };
        for (int i = t; i < 64 * 3; i += 256) {
            int r = row0 + i / 3, chunk = i % 3;
            if (r < N_NODES)
                *(float4*)(h2b + (size_t)r * H2_STR + F_OUT + chunk * 8) = z;
        }
    }
}

// ---------------- layer 2 gather + bias + log_softmax ----------------
// same (o,s) scheme; feats s*8+k, valid < 40; h2b stride 64, padding = 0

__global__ __launch_bounds__(256) void k_agg2_lsm(const __hip_bfloat16* __restrict__ h2b,
                                                  const float* __restrict__ dinv,
                                                  const int* __restrict__ startArr,
                                                  const int* __restrict__ csr,
                                                  const float* __restrict__ b2,
                                                  float* __restrict__ out) {
    int wid  = (blockIdx.x * 256 + threadIdx.x) >> 6;
    int lane = threadIdx.x & 63;
    if (wid >= N_NODES) return;
    const int o = lane >> 3, s = lane & 7;
    const int c = wid;
    const float dc = dinv[c];
    float acc[8] = {};

    if (o == 0) {   // self loop (padding cols are zero)
        float w = dc * dc;
        ushort8_t v = *(const ushort8_t*)(h2b + (size_t)c * H2_STR + s * 8);
        #pragma unroll
        for (int k = 0; k < 8; ++k) acc[k] = fmaf(bf2f(v[k]), w, acc[k]);
    }

    int e = startArr[c], eend = startArr[c + 1];
    while (e < eend) {
        int take = eend - e; if (take > 64) take = 64;
        int r = 0; float w = 0.f;
        if (lane < take) { r = csr[e + lane]; w = dinv[r] * dc; }
        for (int j = 0; j < take; j += 16) {
            int ia = j + o;      ia = ia > 63 ? 63 : ia;
            int ib = j + 8 + o;  ib = ib > 63 ? 63 : ib;
            int   ra = __shfl(r, ia), rb = __shfl(r, ib);
            float wa = __shfl(w, ia), wb = __shfl(w, ib);
            ushort8_t va = *(const ushort8_t*)(h2b + (size_t)ra * H2_STR + s * 8);
            ushort8_t vb = *(const ushort8_t*)(h2b + (size_t)rb * H2_STR + s * 8);
            #pragma unroll
            for (int k = 0; k < 8; ++k) acc[k] = fmaf(bf2f(va[k]), wa, acc[k]);
            #pragma unroll
            for (int k = 0; k < 8; ++k) acc[k] = fmaf(bf2f(vb[k]), wb, acc[k]);
        }
        e += take;
    }

    #pragma unroll
    for (int k = 0; k < 8; ++k) {
        acc[k] += __shfl_xor(acc[k], 8);
        acc[k] += __shfl_xor(acc[k], 16);
        acc[k] += __shfl_xor(acc[k], 32);
    }

    // bias + log_softmax in (o,s) layout; feats f = s*8+k valid iff f < 40 (s < 5)
    float vloc[8];
    float m = -INFINITY;
    if (s < 5) {
        float4 p = *(const float4*)(b2 + s * 8);
        float4 q = *(const float4*)(b2 + s * 8 + 4);
        float bb[8] = { p.x, p.y, p.z, p.w, q.x, q.y, q.z, q.w };
        #pragma unroll
        for (int k = 0; k < 8; ++k) { vloc[k] = acc[k] + bb[k]; m = fmaxf(m, vloc[k]); }
    } else {
        #pragma unroll
        for (int k = 0; k < 8; ++k) vloc[k] = -INFINITY;
    }
    m = fmaxf(m, __shfl_xor(m, 1));
    m = fmaxf(m, __shfl_xor(m, 2));
    m = fmaxf(m, __shfl_xor(m, 4));
    float sum = 0.f;
    if (s < 5) {
        #pragma unroll
        for (int k = 0; k < 8; ++k) sum += expf(vloc[k] - m);
    }
    sum += __shfl_xor(sum, 1);
    sum += __shfl_xor(sum, 2);
    sum += __shfl_xor(sum, 4);
    float ls = m + logf(sum);

    if (o == 0 && s < 5) {
        float4 a = { vloc[0] - ls, vloc[1] - ls, vloc[2] - ls, vloc[3] - ls };
        float4 b = { vloc[4] - ls, vloc[5] - ls, vloc[6] - ls, vloc[7] - ls };
        *(float4*)(out + (size_t)c * F_OUT + s * 8)     = a;
        *(float4*)(out + (size_t)c * F_OUT + s * 8 + 4) = b;
    }
}

// ---------------- launch ----------------

extern "C" void kernel_launch(void* const* d_in, const int* in_sizes, int n_in,
                              void* d_out, int out_size, void* d_ws, size_t ws_size,
                              hipStream_t stream) {
    const float* x     = (const float*)d_in[0];
    const int*   ei    = (const int*)d_in[1];
    const float* W1    = (const float*)d_in[2];
    const float* b1    = (const float*)d_in[3];
    const float* W2    = (const float*)d_in[4];
    const float* b2    = (const float*)d_in[5];
    const float* alpha = (const float*)d_in[6];
    float* out = (float*)d_out;

    // workspace layout (elements)
    int*   startArr  = (int*)d_ws;                        // 50048 ints
    int*   cursor    = startArr + 50048;                  // 50048
    int*   blockSums = cursor + 50048;                    // 256
    int*   csr       = blockSums + 256;                   // 800000
    float* dinv      = (float*)(csr + N_EDGES);           // 50048 floats
    __hip_bfloat16* xb    = (__hip_bfloat16*)(dinv + 50048);   // N*64 bf16 (6.4 MB)
    __hip_bfloat16* agg1b = xb + (size_t)N_NODES * F_IN;       // N*64 bf16
    __hip_bfloat16* h2b   = agg1b + (size_t)N_NODES * F_IN;    // N*64 bf16 padded

    const int B = 256;

    hipLaunchKernelGGL(k_x2bf_zero, dim3((N_NODES * 16 + B - 1) / B), dim3(B), 0, stream, x, xb, startArr);
    hipLaunchKernelGGL(k_count,     dim3((N_EDGES + B - 1) / B), dim3(B), 0, stream, ei, startArr);
    hipLaunchKernelGGL(k_scanA,     dim3(SCAN_BLOCKS), dim3(B), 0, stream, startArr, blockSums);
    hipLaunchKernelGGL(k_scanC,     dim3(SCAN_BLOCKS), dim3(B), 0, stream, startArr, blockSums, cursor, dinv);
    hipLaunchKernelGGL(k_scatter,   dim3(8 * SCAT_CHUNKS), dim3(B), 0, stream, ei, cursor, csr);

    hipLaunchKernelGGL(k_agg1,   dim3((N_NODES * 64 + B - 1) / B), dim3(B), 0, stream, xb, dinv, startArr, csr, agg1b);
    hipLaunchKernelGGL(k_gemm12, dim3((N_NODES + 63) / 64), dim3(B), 0, stream, agg1b, W1, b1, alpha, W2, h2b);
    hipLaunchKernelGGL(k_agg2_lsm, dim3((N_NODES * 64 + B - 1) / B), dim3(B), 0, stream,
                       h2b, dinv, startArr, csr, b2, out);
}